// Round 12
// baseline (1031.280 us; speedup 1.0000x reference)
//
#include <hip/hip_runtime.h>
#include <hip/hip_bf16.h>

#define GN 200000
#define GB 10000
#define GE 600000
#define NCHUNK 98   // ceil(GN/2048)

typedef __bf16 bf16x8 __attribute__((ext_vector_type(8)));
typedef __bf16 bf16x4 __attribute__((ext_vector_type(4)));
typedef float  f32x4  __attribute__((ext_vector_type(4)));

__device__ inline float bfu2f(unsigned int u) {
    union { unsigned int i; float f; } c;
    c.i = u << 16;
    return c.f;
}

// async global->LDS, 16B per lane; lds dest = wave-uniform base + lane*16
__device__ __forceinline__ void g2l16(const void* g, void* l) {
    __builtin_amdgcn_global_load_lds(
        (const __attribute__((address_space(1))) unsigned int*)g,
        (__attribute__((address_space(3))) unsigned int*)l, 16, 0, 0);
}

// ---------------- CSR construction (both graphs fused) ----------------
__global__ void deg2_kernel(const int* __restrict__ dst0, const int* __restrict__ dst1,
                            int* __restrict__ deg) {
    int e = blockIdx.x * 256 + threadIdx.x;
    if (e >= 2 * GE) return;
    int g = e >= GE ? 1 : 0;
    int ee = e - g * GE;
    const int* d = g ? dst1 : dst0;
    atomicAdd(&deg[g * GN + d[ee]], 1);
}

__global__ void scan1_kernel(int* __restrict__ data, int* __restrict__ csum) {
    __shared__ int ls[512];
    int b = blockIdx.x, t = threadIdx.x;
    int g = b >= NCHUNK ? 1 : 0;
    int bb = b - g * NCHUNK;
    int* dp = data + g * GN;
    int base = bb * 2048 + t * 4;
    int v0 = base + 0 < GN ? dp[base + 0] : 0;
    int v1 = base + 1 < GN ? dp[base + 1] : 0;
    int v2 = base + 2 < GN ? dp[base + 2] : 0;
    int v3 = base + 3 < GN ? dp[base + 3] : 0;
    int s = v0 + v1 + v2 + v3;
    ls[t] = s;
    __syncthreads();
    for (int off = 1; off < 512; off <<= 1) {
        int x = (t >= off) ? ls[t - off] : 0;
        __syncthreads();
        ls[t] += x;
        __syncthreads();
    }
    int excl = ls[t] - s;
    if (t == 511) csum[g * 128 + bb] = ls[511];
    if (base + 0 < GN) dp[base + 0] = excl;
    if (base + 1 < GN) dp[base + 1] = excl + v0;
    if (base + 2 < GN) dp[base + 2] = excl + v0 + v1;
    if (base + 3 < GN) dp[base + 3] = excl + v0 + v1 + v2;
}

__global__ void scan2_kernel(int* __restrict__ csum) {
    __shared__ int ls[128];
    int t = threadIdx.x;
    int* cp = csum + blockIdx.x * 128;
    int v = (t < NCHUNK) ? cp[t] : 0;
    ls[t] = v;
    __syncthreads();
    for (int off = 1; off < 128; off <<= 1) {
        int x = (t >= off) ? ls[t - off] : 0;
        __syncthreads();
        ls[t] += x;
        __syncthreads();
    }
    if (t < NCHUNK) cp[t] = ls[t] - v;
}

__global__ void scan3_kernel(int* __restrict__ rowptr, int* __restrict__ cursor,
                             const int* __restrict__ csum) {
    int i = blockIdx.x * 256 + threadIdx.x;
    if (i >= 2 * GN) return;
    int g = i >= GN ? 1 : 0;
    int ii = i - g * GN;
    int v = rowptr[i] + csum[g * 128 + (ii >> 11)];
    rowptr[i] = v;
    cursor[i] = v;
}

__global__ void fill2_kernel(const int* __restrict__ src0, const int* __restrict__ dst0,
                             const int* __restrict__ src1, const int* __restrict__ dst1,
                             int* __restrict__ cursor, int* __restrict__ eidx) {
    int e = blockIdx.x * 256 + threadIdx.x;
    if (e >= 2 * GE) return;
    int g = e >= GE ? 1 : 0;
    int ee = e - g * GE;
    const int* s = g ? src1 : src0;
    const int* d = g ? dst1 : dst0;
    int p = atomicAdd(&cursor[g * GN + d[ee]], 1);
    eidx[g * GE + p] = s[ee];
}

// ---------------- message passing ----------------
__global__ void msg1_kernel(const float* __restrict__ x0, const float* __restrict__ x1,
                            const int* __restrict__ rowptr, const int* __restrict__ cursor,
                            const int* __restrict__ eidx, float* __restrict__ msg1) {
    int i = blockIdx.x * 256 + threadIdx.x;
    if (i >= 2 * GN) return;
    int g = i >= GN ? 1 : 0;
    const float* x = g ? x1 : x0;
    const int* ei = eidx + g * GE;
    int k = rowptr[i], k1 = cursor[i];
    float a0 = 0.f, a1 = 0.f;
    for (; k + 1 < k1; k += 2) {
        int sa = ei[k], sb = ei[k + 1];
        float2 va = *(const float2*)&x[sa * 2];
        float2 vb = *(const float2*)&x[sb * 2];
        a0 += va.x + vb.x;
        a1 += va.y + vb.y;
    }
    if (k < k1) {
        int sa = ei[k];
        float2 va = *(const float2*)&x[sa * 2];
        a0 += va.x;
        a1 += va.y;
    }
    msg1[i * 2] = a0;
    msg1[i * 2 + 1] = a1;
}

// wave per node; gm row = [hi 256ch | lo 256ch] (stride 512).
__global__ void msg2_csr_kernel(const __bf16* __restrict__ gmI,
                                const int* __restrict__ rowptr, const int* __restrict__ cursor,
                                const int* __restrict__ eidx, __bf16* __restrict__ gmO) {
    int wid = (blockIdx.x * 256 + threadIdx.x) >> 6;
    int lane = threadIdx.x & 63;
    if (wid >= GN) return;
    int k = rowptr[wid], k1 = cursor[wid];
    const int roff = ((lane & 32) << 3) + (lane & 31) * 4;   // hi: 0..127, lo: 256..383
    float a0 = 0.f, a1 = 0.f, a2 = 0.f, a3 = 0.f;
    for (; k + 1 < k1; k += 2) {
        int sa = eidx[k], sb = eidx[k + 1];
        uint2 va = *(const uint2*)&gmI[(size_t)sa * 512 + roff];
        uint2 vb = *(const uint2*)&gmI[(size_t)sb * 512 + roff];
        a0 += bfu2f(va.x & 0xffffu) + bfu2f(vb.x & 0xffffu);
        a1 += bfu2f(va.x >> 16)     + bfu2f(vb.x >> 16);
        a2 += bfu2f(va.y & 0xffffu) + bfu2f(vb.y & 0xffffu);
        a3 += bfu2f(va.y >> 16)     + bfu2f(vb.y >> 16);
    }
    if (k < k1) {
        int sa = eidx[k];
        uint2 va = *(const uint2*)&gmI[(size_t)sa * 512 + roff];
        a0 += bfu2f(va.x & 0xffffu);
        a1 += bfu2f(va.x >> 16);
        a2 += bfu2f(va.y & 0xffffu);
        a3 += bfu2f(va.y >> 16);
    }
    a0 += __shfl_xor(a0, 32);
    a1 += __shfl_xor(a1, 32);
    a2 += __shfl_xor(a2, 32);
    a3 += __shfl_xor(a3, 32);
    __bf16 h0 = (__bf16)a0, h1 = (__bf16)a1, h2 = (__bf16)a2, h3 = (__bf16)a3;
    bf16x4 outv;
    if (lane < 32) outv = (bf16x4){h0, h1, h2, h3};
    else outv = (bf16x4){(__bf16)(a0 - (float)h0), (__bf16)(a1 - (float)h1),
                         (__bf16)(a2 - (float)h2), (__bf16)(a3 - (float)h3)};
    int woff = 128 + ((lane & 32) << 3) + (lane & 31) * 4;
    *(bf16x4*)&gmO[(size_t)wid * 512 + woff] = outv;
}

// ---------------- conv layer 1: writes split g1 into interleaved gm ----------------
__global__ void conv1_kernel(const float* __restrict__ x, const float* __restrict__ msg1,
                             const float* __restrict__ W1r, const float* __restrict__ W1n,
                             const float* __restrict__ b1, __bf16* __restrict__ gmI) {
    int idx = blockIdx.x * 256 + threadIdx.x;
    int n = idx >> 4, c8 = (idx & 15) << 3;
    float x0 = x[n * 2], x1 = x[n * 2 + 1];
    float m0 = msg1[n * 2], m1 = msg1[n * 2 + 1];
    bf16x8 hv, lv;
#pragma unroll
    for (int e = 0; e < 8; ++e) {
        int c = c8 + e;
        float v = b1[c];
        v = fmaf(x0, W1r[c * 2], v);
        v = fmaf(x1, W1r[c * 2 + 1], v);
        v = fmaf(m0, W1n[c * 2], v);
        v = fmaf(m1, W1n[c * 2 + 1], v);
        v = v >= 0.f ? v : 0.01f * v;
        __bf16 h = (__bf16)v;
        hv[e] = h;
        lv[e] = (__bf16)(v - (float)h);
    }
    *(bf16x8*)&gmI[(size_t)n * 512 + c8] = hv;
    *(bf16x8*)&gmI[(size_t)n * 512 + 256 + c8] = lv;
}

// ---------------- merged weight prep (wcat + 4 MLP weights), total 589,824 elems ----------------
__global__ void prep_all(const float* __restrict__ W2r, const float* __restrict__ W2n,
                         const float* __restrict__ nW1, const float* __restrict__ nW2,
                         const float* __restrict__ eW1, const float* __restrict__ eW2,
                         __bf16* __restrict__ wcat_hi, __bf16* __restrict__ wcat_lo,
                         __bf16* __restrict__ nW1hi, __bf16* __restrict__ nW1lo,
                         __bf16* __restrict__ nW2hi, __bf16* __restrict__ nW2lo,
                         __bf16* __restrict__ eW1hi, __bf16* __restrict__ eW1lo,
                         __bf16* __restrict__ eW2hi, __bf16* __restrict__ eW2lo) {
    int i = blockIdx.x * 256 + threadIdx.x;
    float v; __bf16 *hi, *lo; int off;
    if (i < 65536) {
        int c = i >> 8, k = i & 255;
        v = (k < 128) ? W2r[c * 128 + k] : W2n[c * 128 + (k - 128)];
        hi = wcat_hi; lo = wcat_lo; off = i;
    } else if (i < 131072) {
        off = i - 65536;  v = nW1[off]; hi = nW1hi; lo = nW1lo;
    } else if (i < 262144) {
        off = i - 131072; v = nW2[off]; hi = nW2hi; lo = nW2lo;
    } else if (i < 458752) {
        off = i - 262144; v = eW1[off]; hi = eW1hi; lo = eW1lo;
    } else {
        off = i - 458752; v = eW2[off]; hi = eW2hi; lo = eW2lo;
    }
    __bf16 h = (__bf16)v;
    hi[off] = h;
    lo[off] = (__bf16)(v - (float)h);
}

// ---------------- conv2 GEMM v8: B-RESIDENT LDS, A-only counted-vmcnt dbuf ----------------
// Block = 128 rows x 128 cols, 512 thr (8 waves: wr=row-half 0..1, wc=col-quarter 0..3;
// wave tile 64r x 32c, acc[4][2]). LDS: A2 dbuf 2x16KB + B1 128KB = 160KB (1 block/CU).
// B loaded ONCE in prologue (L2-resident weights); K-loop stages only A (2 g2l16/thread,
// vmcnt(2) steady-state). Swizzle: B col c slot s holds source slot s^(c&7);
// A row r slot s holds source slot s^(r&7). gm rows interleaved [hi|lo] stride 512.
template <int MODE>
__global__ __launch_bounds__(512, 2)
void conv2_gemm(const __bf16* __restrict__ A,
                const __bf16* __restrict__ whi, const __bf16* __restrict__ wlo,
                const float* __restrict__ bias,
                float* __restrict__ out, int ldo, int M, int ctiles,
                const int* __restrict__ aux, const int* __restrict__ aux2) {
    __shared__ __attribute__((aligned(16))) __bf16 A2[2][128 * 64];   // 32 KB
    __shared__ __attribute__((aligned(16))) __bf16 B1[128 * 512];     // 128 KB
    const int tid = threadIdx.x, lane = tid & 63, wv = tid >> 6;
    const int fr = lane & 15, kq = lane >> 4;
    const int wr = wv >> 2, wc = wv & 3;
    const int bm = (blockIdx.x / ctiles) * 128;
    const int bn = (blockIdx.x % ctiles) * 128;

    // ---- A staging sources (per-lane), rows 0..127 ----
    const __bf16* asrc[2]; int adst[2];
#pragma unroll
    for (int j = 0; j < 2; ++j) {
        int a = wv * 2 + j;                 // 0..15 -> rows a*8..a*8+7
        int row = a * 8 + (lane >> 3);
        int slot = (lane & 7) ^ (row & 7);
        int m = bm + row;
        long r;
        if (MODE == 2) r = (m < M) ? (long)(m < GB ? aux[m] : aux2[m - GB]) : 0;
        else           r = (m < M) ? m : (M - 1);
        asrc[j] = A + r * 512 + (slot < 4 ? 0 : 256) + (slot & 3) * 8;
        adst[j] = a * 512;
    }
    // ---- A fragment LDS offsets ----
    int aoh[4], aol[4];
#pragma unroll
    for (int mt = 0; mt < 4; ++mt) {
        int row = wr * 64 + mt * 16 + fr;
        aoh[mt] = row * 64 + ((kq       ^ (row & 7)) * 8);
        aol[mt] = row * 64 + (((kq | 4) ^ (row & 7)) * 8);
    }

    f32x4 acc[4][2];
#pragma unroll
    for (int i = 0; i < 4; ++i)
#pragma unroll
        for (int j = 0; j < 2; ++j) acc[i][j] = (f32x4){0.f, 0.f, 0.f, 0.f};

    // ---- prologue: B resident (16 issues/wave), then A stage 0,1 ----
#pragma unroll
    for (int j = 0; j < 16; ++j) {
        int c = wv * 16 + j;                // local col 0..127
        int sl = lane ^ (c & 7);            // source slot for this lane
        const __bf16* src = ((sl < 32) ? whi : wlo) + (size_t)(bn + c) * 256 + (sl & 31) * 8;
        g2l16(src, &B1[c * 512]);
    }
    g2l16(asrc[0], &A2[0][adst[0]]);
    g2l16(asrc[1], &A2[0][adst[1]]);
    g2l16(asrc[0] + 32, &A2[1][adst[0]]);
    g2l16(asrc[1] + 32, &A2[1][adst[1]]);

#pragma unroll
    for (int t = 0; t < 8; ++t) {
        const int cur = t & 1;
        if (t < 7) asm volatile("s_waitcnt vmcnt(2)" ::: "memory");
        else       asm volatile("s_waitcnt vmcnt(0)" ::: "memory");
        __builtin_amdgcn_s_barrier();

        bf16x8 ah[4], al[4], bh[2], bl[2];
#pragma unroll
        for (int mt = 0; mt < 4; ++mt) {
            ah[mt] = *(const bf16x8*)&A2[cur][aoh[mt]];
            al[mt] = *(const bf16x8*)&A2[cur][aol[mt]];
        }
#pragma unroll
        for (int nt = 0; nt < 2; ++nt) {
            int c = wc * 32 + nt * 16 + fr;
            bh[nt] = *(const bf16x8*)&B1[c * 512 + (((4 * t + kq)      ^ (c & 7)) * 8)];
            bl[nt] = *(const bf16x8*)&B1[c * 512 + (((32 + 4 * t + kq) ^ (c & 7)) * 8)];
        }
        asm volatile("s_waitcnt lgkmcnt(0)" ::: "memory");
        __builtin_amdgcn_sched_barrier(0);
        __builtin_amdgcn_s_barrier();

        if (t + 2 < 8) {
            int ks = (t + 2) * 32;
            g2l16(asrc[0] + ks, &A2[cur][adst[0]]);
            g2l16(asrc[1] + ks, &A2[cur][adst[1]]);
        }
#pragma unroll
        for (int mt = 0; mt < 4; ++mt)
#pragma unroll
            for (int nt = 0; nt < 2; ++nt) {
                acc[mt][nt] = __builtin_amdgcn_mfma_f32_16x16x32_bf16(ah[mt], bh[nt], acc[mt][nt], 0, 0, 0);
                acc[mt][nt] = __builtin_amdgcn_mfma_f32_16x16x32_bf16(ah[mt], bl[nt], acc[mt][nt], 0, 0, 0);
                acc[mt][nt] = __builtin_amdgcn_mfma_f32_16x16x32_bf16(al[mt], bh[nt], acc[mt][nt], 0, 0, 0);
            }
    }

    // ---- epilogue ----
    const int q4 = kq * 4;
    const int cbg = bn + wc * 32;       // wave's global col base (32 cols, nt 0..1)
    const int rbg = bm + wr * 64;

    if (MODE == 1) {
        float s0 = 0.f, s1 = 0.f;
        int cur2 = -1;
        float bi0 = bias[cbg + fr], bi1 = bias[cbg + 16 + fr];
#pragma unroll
        for (int mt = 0; mt < 4; ++mt) {
#pragma unroll
            for (int j = 0; j < 4; ++j) {
                int m = rbg + mt * 16 + q4 + j;
                if (m < M) {
                    float v0 = acc[mt][0][j] + bi0;
                    float v1 = acc[mt][1][j] + bi1;
                    v0 = v0 >= 0.f ? v0 : 0.01f * v0;
                    v1 = v1 >= 0.f ? v1 : 0.01f * v1;
                    int b = aux[m];
                    if (b != cur2) {
                        if (cur2 >= 0) {
                            atomicAdd(&out[(size_t)cur2 * ldo + cbg + fr], s0);
                            atomicAdd(&out[(size_t)cur2 * ldo + cbg + 16 + fr], s1);
                        }
                        cur2 = b; s0 = v0; s1 = v1;
                    } else {
                        s0 += v0; s1 += v1;
                    }
                }
            }
        }
        if (cur2 >= 0) {
            atomicAdd(&out[(size_t)cur2 * ldo + cbg + fr], s0);
            atomicAdd(&out[(size_t)cur2 * ldo + cbg + 16 + fr], s1);
        }
    } else {
#pragma unroll
        for (int mt = 0; mt < 4; ++mt) {
#pragma unroll
            for (int j = 0; j < 4; ++j) {
                int m = rbg + mt * 16 + q4 + j;
                if (m >= M) continue;
                int orow = (m < GB) ? m : m - GB;
                int ocol = (m < GB) ? 256 : 512;
                size_t obase = (size_t)orow * ldo + ocol;
#pragma unroll
                for (int nt = 0; nt < 2; ++nt) {
                    int cc = cbg + nt * 16 + fr;
                    float v = acc[mt][nt][j] + bias[cc];
                    v = v >= 0.f ? v : 0.01f * v;
                    out[obase + cc] = v;
                }
            }
        }
    }
}

// ---------------- MLP GEMM: BM=64 x BN=64 per block, wave = 16 rows x 64 cols ----------------
template <int PRESPLIT, int OSPLIT>
__global__ __launch_bounds__(256, 4)
void mlp_gemm(const float* __restrict__ Af,
              const __bf16* __restrict__ Agh, const __bf16* __restrict__ Agl, int lda,
              const __bf16* __restrict__ whi, const __bf16* __restrict__ wlo,
              const float* __restrict__ bias,
              float* __restrict__ out, __bf16* __restrict__ outh, __bf16* __restrict__ outl,
              int ldo, int M, int K, int ctiles) {
    __shared__ __bf16 Ah[64][40], Al[64][40];
    const int bm = (blockIdx.x / ctiles) * 64;
    const int bn = (blockIdx.x % ctiles) * 64;
    const int tid = threadIdx.x, lane = tid & 63, wv = tid >> 6;

    const int sar = tid >> 2;
    const int sak = (tid & 3) * 8;
    const int arow = bm + sar;
    long asrc = arow < M ? arow : M - 1;
    const float*  Arf = PRESPLIT ? nullptr : (Af + (size_t)asrc * lda);
    const __bf16* Arh = PRESPLIT ? (Agh + (size_t)asrc * lda) : nullptr;
    const __bf16* Arl = PRESPLIT ? (Agl + (size_t)asrc * lda) : nullptr;

    const int fr = lane & 15, kg = (lane >> 4) * 8;

    const __bf16* bph[4];
    const __bf16* bpl[4];
#pragma unroll
    for (int nt = 0; nt < 4; ++nt) {
        bph[nt] = whi + (size_t)(bn + nt * 16 + fr) * K + kg;
        bpl[nt] = wlo + (size_t)(bn + nt * 16 + fr) * K + kg;
    }

    f32x4 acc[4];
#pragma unroll
    for (int j = 0; j < 4; ++j) acc[j] = (f32x4){0.f, 0.f, 0.f, 0.f};

    for (int ks = 0; ks < K; ks += 32) {
        uint4 hv, lv;
        if (PRESPLIT) {
            hv = *(const uint4*)(Arh + ks + sak);
            lv = *(const uint4*)(Arl + ks + sak);
        } else {
            float4 a0 = *(const float4*)(Arf + ks + sak);
            float4 a1 = *(const float4*)(Arf + ks + sak + 4);
            float va[8] = {a0.x, a0.y, a0.z, a0.w, a1.x, a1.y, a1.z, a1.w};
            bf16x8 h8, l8;
#pragma unroll
            for (int e = 0; e < 8; ++e) {
                float v = va[e];
                __bf16 h = (__bf16)v;
                h8[e] = h;
                l8[e] = (__bf16)(v - (float)h);
            }
            hv = *(uint4*)&h8;
            lv = *(uint4*)&l8;
        }
        __syncthreads();
        *(uint4*)&Ah[sar][sak] = hv;
        *(uint4*)&Al[sar][sak] = lv;
        __syncthreads();

        bf16x8 ahf, alf, bh[4], bl[4];
        ahf = *(const bf16x8*)&Ah[wv * 16 + fr][kg];
        alf = *(const bf16x8*)&Al[wv * 16 + fr][kg];
#pragma unroll
        for (int nt = 0; nt < 4; ++nt) {
            bh[nt] = *(const bf16x8*)(bph[nt] + ks);
            bl[nt] = *(const bf16x8*)(bpl[nt] + ks);
        }
#pragma unroll
        for (int nt = 0; nt < 4; ++nt) {
            acc[nt] = __builtin_amdgcn_mfma_f32_16x16x32_bf16(ahf, bh[nt], acc[nt], 0, 0, 0);
            acc[nt] = __builtin_amdgcn_mfma_f32_16x16x32_bf16(ahf, bl[nt], acc[nt], 0, 0, 0);
            acc[nt] = __builtin_amdgcn_mfma_f32_16x16x32_bf16(alf, bh[nt], acc[nt], 0, 0, 0);
        }
    }

    const int q4 = (lane >> 4) * 4;
#pragma unroll
    for (int j = 0; j < 4; ++j) {
        int m = bm + wv * 16 + q4 + j;
        if (m >= M) continue;
        size_t obase = (size_t)m * ldo;
#pragma unroll
        for (int nt = 0; nt < 4; ++nt) {
            int cc = bn + nt * 16 + fr;
            float v = tanhf(acc[nt][j] + bias[cc]);
            if (OSPLIT) {
                __bf16 h = (__bf16)v;
                outh[obase + cc] = h;
                outl[obase + cc] = (__bf16)(v - (float)h);
            } else {
                out[obase + cc] = v;
            }
        }
    }
}

// ---------------- output head: wave per (b,o), coalesced + shfl reduce ----------------
__global__ void outhead_kernel(const float* __restrict__ h, const float* __restrict__ W,
                               const float* __restrict__ bias, float* __restrict__ yp,
                               int total, int nout) {
    int w = (blockIdx.x * 256 + threadIdx.x) >> 6;
    int lane = threadIdx.x & 63;
    if (w >= total) return;
    int b = w / nout, o = w - b * nout;
    const float4* hr = (const float4*)(h + (size_t)b * 512) + lane * 2;
    const float4* wr = (const float4*)(W + (size_t)o * 512) + lane * 2;
    float4 h0 = hr[0], h1 = hr[1], w0 = wr[0], w1 = wr[1];
    float s = h0.x * w0.x + h0.y * w0.y + h0.z * w0.z + h0.w * w0.w +
              h1.x * w1.x + h1.y * w1.y + h1.z * w1.z + h1.w * w1.w;
#pragma unroll
    for (int off = 32; off >= 1; off >>= 1) s += __shfl_down(s, off);
    if (lane == 0) yp[w] = s + bias[o];
}

// ---------------- losses ----------------
__global__ void loss_kernel(const float* __restrict__ ypx, const float* __restrict__ ypA,
                            const float* __restrict__ y_x, const float* __restrict__ y_A,
                            float* __restrict__ out) {
    int b = blockIdx.x * 256 + threadIdx.x;
    if (b >= GB) return;
#pragma unroll
    for (int j = 0; j < 2; ++j) {
        float p  = ypx[b * 4 + j];
        float a  = p * p + 1e-7f;
        float mu = ypx[b * 4 + 2 + j];
        float e  = (y_x[b * 2 + j] - mu) / a;
        out[b * 2 + j] = e * e + logf(a);
    }
    float p  = ypA[b * 2 + 0];
    float a  = p * p + 1e-7f;
    float mu = ypA[b * 2 + 1];
    float e  = (y_A[b] - mu) / a;
    out[2 * GB + b] = e * e + logf(a);
}

extern "C" void kernel_launch(void* const* d_in, const int* in_sizes, int n_in,
                              void* d_out, int out_size, void* d_ws, size_t ws_size,
                              hipStream_t stream) {
    const float* x_x     = (const float*)d_in[0];
    const float* y_x     = (const float*)d_in[1];
    const int*   ei_x    = (const int*)d_in[2];
    const int*   batch_x = (const int*)d_in[3];
    const float* x_A     = (const float*)d_in[4];
    const float* y_A     = (const float*)d_in[5];
    const int*   ei_A    = (const int*)d_in[6];
    const int*   batch_A = (const int*)d_in[7];
    const int*   idi_A   = (const int*)d_in[8];
    const int*   idj_A   = (const int*)d_in[9];
    const float* W1r = (const float*)d_in[10];
    const float* W1n = (const float*)d_in[11];
    const float* b1  = (const float*)d_in[12];
    const float* W2r = (const float*)d_in[13];
    const float* W2n = (const float*)d_in[14];
    const float* b2  = (const float*)d_in[15];
    const float* nW1 = (const float*)d_in[16];
    const float* nb1 = (const float*)d_in[17];
    const float* nW2 = (const float*)d_in[18];
    const float* nb2 = (const float*)d_in[19];
    const float* nW3 = (const float*)d_in[20];
    const float* nb3 = (const float*)d_in[21];
    const float* eW1 = (const float*)d_in[22];
    const float* eb1 = (const float*)d_in[23];
    const float* eW2 = (const float*)d_in[24];
    const float* eb2 = (const float*)d_in[25];
    const float* eW3 = (const float*)d_in[26];
    const float* eb3 = (const float*)d_in[27];

    // ---- workspace layout ----
    __bf16* gmI  = (__bf16*)d_ws;                    // GN*512 (interleaved hi|lo)
    float*  msg1 = (float*)(gmI + (size_t)GN * 512); // 2*GN*2
    float*  rgx  = msg1 + (size_t)2 * GN * 2;        // GB*256
    float*  use  = rgx  + (size_t)GB * 256;          // GB*768
    __bf16* wcat_hi = (__bf16*)(use + (size_t)GB * 768);
    __bf16* wcat_lo = wcat_hi + 65536;
    __bf16* nW1hi = wcat_lo + 65536;
    __bf16* nW1lo = nW1hi + 65536;
    __bf16* nW2hi = nW1lo + 65536;
    __bf16* nW2lo = nW2hi + 131072;
    __bf16* eW1hi = nW2lo + 131072;
    __bf16* eW1lo = eW1hi + 196608;
    __bf16* eW2hi = eW1lo + 196608;
    __bf16* eW2lo = eW2hi + 131072;
    int* rowptr = (int*)(eW2lo + 131072);            // 2*GN
    int* cursor = rowptr + 2 * GN;                   // 2*GN
    int* eidx   = cursor + 2 * GN;                   // 2*GE
    int* csum   = eidx + 2 * GE;                     // 256
    char* wend  = (char*)(csum + 256);
    // aliases into gmI region (dead after sel-GEMM):
    __bf16* h1h = gmI;
    __bf16* h1l = h1h + (size_t)GB * 256;
    float*  h2  = (float*)(h1l + (size_t)GB * 256);
    float*  ypx = h2 + (size_t)GB * 512;
    float*  ypA = ypx + (size_t)GB * 4;

    size_t need = (size_t)(wend - (char*)d_ws);
    if (ws_size < need) return;

    float* out = (float*)d_out;

    // merged weight prep: 589,824 elems / 256 = 2304 blocks
    prep_all<<<2304, 256, 0, stream>>>(W2r, W2n, nW1, nW2, eW1, eW2,
                                       wcat_hi, wcat_lo, nW1hi, nW1lo, nW2hi, nW2lo,
                                       eW1hi, eW1lo, eW2hi, eW2lo);

    // CSR + msg1 for BOTH graphs, fused
    hipMemsetAsync(rowptr, 0, (size_t)2 * GN * sizeof(int), stream);
    deg2_kernel<<<(2 * GE + 255) / 256, 256, 0, stream>>>(ei_x + GE, ei_A + GE, rowptr);
    scan1_kernel<<<2 * NCHUNK, 512, 0, stream>>>(rowptr, csum);
    scan2_kernel<<<2, 128, 0, stream>>>(csum);
    scan3_kernel<<<(2 * GN + 255) / 256, 256, 0, stream>>>(rowptr, cursor, csum);
    fill2_kernel<<<(2 * GE + 255) / 256, 256, 0, stream>>>(ei_x, ei_x + GE, ei_A, ei_A + GE,
                                                           cursor, eidx);
    msg1_kernel<<<(2 * GN + 255) / 256, 256, 0, stream>>>(x_x, x_A, rowptr, cursor, eidx, msg1);

    // zero both readout buffers in one shot (contiguous)
    hipMemsetAsync(rgx, 0, (size_t)(GB * 256 + GB * 768) * sizeof(float), stream);

    const int conv2_grid = ((GN + 127) / 128) * 2;   // 1563 row-tiles x 2 col-tiles
    const int sel_grid   = ((2 * GB + 127) / 128) * 2;

    for (int g = 0; g < 2; ++g) {
        const float* x = g == 0 ? x_x : x_A;
        const int* rp  = rowptr + g * GN;
        const int* cu  = cursor + g * GN;
        const int* ei  = eidx + (size_t)g * GE;
        const int* bat = g == 0 ? batch_x : batch_A;

        conv1_kernel<<<GN * 16 / 256, 256, 0, stream>>>(x, msg1 + (size_t)g * GN * 2,
                                                        W1r, W1n, b1, gmI);
        msg2_csr_kernel<<<GN / 4, 256, 0, stream>>>(gmI, rp, cu, ei, gmI);

        if (g == 0) {
            conv2_gemm<1><<<conv2_grid, 512, 0, stream>>>(
                gmI, wcat_hi, wcat_lo, b2, rgx, 256, GN, 2, bat, nullptr);
        } else {
            conv2_gemm<1><<<conv2_grid, 512, 0, stream>>>(
                gmI, wcat_hi, wcat_lo, b2, use, 768, GN, 2, bat, nullptr);
            conv2_gemm<2><<<sel_grid, 512, 0, stream>>>(
                gmI, wcat_hi, wcat_lo, b2, use, 768, 2 * GB, 2, idi_A, idj_A);
        }
    }

    const int mlp_mt = (GB + 63) / 64;   // 157

    // node MLP (h1/h2 alias gmI region; gm dead now)
    mlp_gemm<0, 1><<<mlp_mt * 4, 256, 0, stream>>>(
        rgx, nullptr, nullptr, 256, nW1hi, nW1lo, nb1,
        nullptr, h1h, h1l, 256, GB, 256, 4);
    mlp_gemm<1, 0><<<mlp_mt * 8, 256, 0, stream>>>(
        nullptr, h1h, h1l, 256, nW2hi, nW2lo, nb2,
        h2, nullptr, nullptr, 512, GB, 256, 8);
    outhead_kernel<<<(GB * 4 * 64 + 255) / 256, 256, 0, stream>>>(h2, nW3, nb3, ypx, GB * 4, 4);

    // edge MLP
    mlp_gemm<0, 1><<<mlp_mt * 4, 256, 0, stream>>>(
        use, nullptr, nullptr, 768, eW1hi, eW1lo, eb1,
        nullptr, h1h, h1l, 256, GB, 768, 4);
    mlp_gemm<1, 0><<<mlp_mt * 8, 256, 0, stream>>>(
        nullptr, h1h, h1l, 256, eW2hi, eW2lo, eb2,
        h2, nullptr, nullptr, 512, GB, 256, 8);
    outhead_kernel<<<(GB * 2 * 64 + 255) / 256, 256, 0, stream>>>(h2, eW3, eb3, ypA, GB * 2, 2);

    loss_kernel<<<(GB + 255) / 256, 256, 0, stream>>>(ypx, ypA, y_x, y_A, out);
}

// Round 13
// 986.780 us; speedup vs baseline: 1.0451x; 1.0451x over previous
//
#include <hip/hip_runtime.h>
#include <hip/hip_bf16.h>

#define GN 200000
#define GB 10000
#define GE 600000
#define NCHUNK 98   // ceil(GN/2048)

typedef __bf16 bf16x8 __attribute__((ext_vector_type(8)));
typedef __bf16 bf16x4 __attribute__((ext_vector_type(4)));
typedef float  f32x4  __attribute__((ext_vector_type(4)));

__device__ inline float bfu2f(unsigned int u) {
    union { unsigned int i; float f; } c;
    c.i = u << 16;
    return c.f;
}

// async global->LDS, 16B per lane; lds dest = wave-uniform base + lane*16
__device__ __forceinline__ void g2l16(const void* g, void* l) {
    __builtin_amdgcn_global_load_lds(
        (const __attribute__((address_space(1))) unsigned int*)g,
        (__attribute__((address_space(3))) unsigned int*)l, 16, 0, 0);
}

// ---------------- CSR construction (both graphs fused) ----------------
__global__ void deg2_kernel(const int* __restrict__ dst0, const int* __restrict__ dst1,
                            int* __restrict__ deg) {
    int e = blockIdx.x * 256 + threadIdx.x;
    if (e >= 2 * GE) return;
    int g = e >= GE ? 1 : 0;
    int ee = e - g * GE;
    const int* d = g ? dst1 : dst0;
    atomicAdd(&deg[g * GN + d[ee]], 1);
}

__global__ void scan1_kernel(int* __restrict__ data, int* __restrict__ csum) {
    __shared__ int ls[512];
    int b = blockIdx.x, t = threadIdx.x;
    int g = b >= NCHUNK ? 1 : 0;
    int bb = b - g * NCHUNK;
    int* dp = data + g * GN;
    int base = bb * 2048 + t * 4;
    int v0 = base + 0 < GN ? dp[base + 0] : 0;
    int v1 = base + 1 < GN ? dp[base + 1] : 0;
    int v2 = base + 2 < GN ? dp[base + 2] : 0;
    int v3 = base + 3 < GN ? dp[base + 3] : 0;
    int s = v0 + v1 + v2 + v3;
    ls[t] = s;
    __syncthreads();
    for (int off = 1; off < 512; off <<= 1) {
        int x = (t >= off) ? ls[t - off] : 0;
        __syncthreads();
        ls[t] += x;
        __syncthreads();
    }
    int excl = ls[t] - s;
    if (t == 511) csum[g * 128 + bb] = ls[511];
    if (base + 0 < GN) dp[base + 0] = excl;
    if (base + 1 < GN) dp[base + 1] = excl + v0;
    if (base + 2 < GN) dp[base + 2] = excl + v0 + v1;
    if (base + 3 < GN) dp[base + 3] = excl + v0 + v1 + v2;
}

__global__ void scan2_kernel(int* __restrict__ csum) {
    __shared__ int ls[128];
    int t = threadIdx.x;
    int* cp = csum + blockIdx.x * 128;
    int v = (t < NCHUNK) ? cp[t] : 0;
    ls[t] = v;
    __syncthreads();
    for (int off = 1; off < 128; off <<= 1) {
        int x = (t >= off) ? ls[t - off] : 0;
        __syncthreads();
        ls[t] += x;
        __syncthreads();
    }
    if (t < NCHUNK) cp[t] = ls[t] - v;
}

__global__ void scan3_kernel(int* __restrict__ rowptr, int* __restrict__ cursor,
                             const int* __restrict__ csum) {
    int i = blockIdx.x * 256 + threadIdx.x;
    if (i >= 2 * GN) return;
    int g = i >= GN ? 1 : 0;
    int ii = i - g * GN;
    int v = rowptr[i] + csum[g * 128 + (ii >> 11)];
    rowptr[i] = v;
    cursor[i] = v;
}

__global__ void fill2_kernel(const int* __restrict__ src0, const int* __restrict__ dst0,
                             const int* __restrict__ src1, const int* __restrict__ dst1,
                             int* __restrict__ cursor, int* __restrict__ eidx) {
    int e = blockIdx.x * 256 + threadIdx.x;
    if (e >= 2 * GE) return;
    int g = e >= GE ? 1 : 0;
    int ee = e - g * GE;
    const int* s = g ? src1 : src0;
    const int* d = g ? dst1 : dst0;
    int p = atomicAdd(&cursor[g * GN + d[ee]], 1);
    eidx[g * GE + p] = s[ee];
}

// ---------------- message passing ----------------
__global__ void msg1_kernel(const float* __restrict__ x0, const float* __restrict__ x1,
                            const int* __restrict__ rowptr, const int* __restrict__ cursor,
                            const int* __restrict__ eidx, float* __restrict__ msg1) {
    int i = blockIdx.x * 256 + threadIdx.x;
    if (i >= 2 * GN) return;
    int g = i >= GN ? 1 : 0;
    const float* x = g ? x1 : x0;
    const int* ei = eidx + g * GE;
    int k = rowptr[i], k1 = cursor[i];
    float a0 = 0.f, a1 = 0.f;
    for (; k + 1 < k1; k += 2) {
        int sa = ei[k], sb = ei[k + 1];
        float2 va = *(const float2*)&x[sa * 2];
        float2 vb = *(const float2*)&x[sb * 2];
        a0 += va.x + vb.x;
        a1 += va.y + vb.y;
    }
    if (k < k1) {
        int sa = ei[k];
        float2 va = *(const float2*)&x[sa * 2];
        a0 += va.x;
        a1 += va.y;
    }
    msg1[i * 2] = a0;
    msg1[i * 2 + 1] = a1;
}

// msg2 v2: RECOMPUTE g1[src] from x[src], msg1[src] (16B/edge instead of 512B/edge).
// Wave per dst node; lane owns 4 channels c0=(lane&31)*4; lanes 0-31 write hi, 32-63 lo
// (redundant compute, no shuffles). Weights held in registers.
__global__ void msg2_csr_kernel(const float* __restrict__ x, const float* __restrict__ msg1g,
                                const float* __restrict__ W1r, const float* __restrict__ W1n,
                                const float* __restrict__ b1,
                                const int* __restrict__ rowptr, const int* __restrict__ cursor,
                                const int* __restrict__ eidx, __bf16* __restrict__ gmO) {
    int wid = (blockIdx.x * 256 + threadIdx.x) >> 6;
    int lane = threadIdx.x & 63;
    if (wid >= GN) return;
    const int c0 = (lane & 31) * 4;
    // per-lane weights for 4 channels
    float wr0[4], wr1[4], wn0[4], wn1[4], bb[4], acc[4];
#pragma unroll
    for (int j = 0; j < 4; ++j) {
        int c = c0 + j;
        float2 wr = *(const float2*)&W1r[c * 2];
        float2 wn = *(const float2*)&W1n[c * 2];
        wr0[j] = wr.x; wr1[j] = wr.y;
        wn0[j] = wn.x; wn1[j] = wn.y;
        bb[j] = b1[c];
        acc[j] = 0.f;
    }
    int k = rowptr[wid], k1 = cursor[wid];
    for (; k < k1; ++k) {
        int s = eidx[k];
        float2 xv = *(const float2*)&x[s * 2];
        float2 mv = *(const float2*)&msg1g[s * 2];
#pragma unroll
        for (int j = 0; j < 4; ++j) {
            float v = bb[j];
            v = fmaf(xv.x, wr0[j], v);
            v = fmaf(xv.y, wr1[j], v);
            v = fmaf(mv.x, wn0[j], v);
            v = fmaf(mv.y, wn1[j], v);
            v = v >= 0.f ? v : 0.01f * v;
            acc[j] += v;
        }
    }
    bf16x4 outv;
    if (lane < 32) {
        outv = (bf16x4){(__bf16)acc[0], (__bf16)acc[1], (__bf16)acc[2], (__bf16)acc[3]};
    } else {
#pragma unroll
        for (int j = 0; j < 4; ++j) {
            __bf16 h = (__bf16)acc[j];
            acc[j] = acc[j] - (float)h;
        }
        outv = (bf16x4){(__bf16)acc[0], (__bf16)acc[1], (__bf16)acc[2], (__bf16)acc[3]};
    }
    // interleaved row [hi 0..255 | lo 0..255]; msg2 ch = 128+c0 -> hi at 128+c0, lo at 384+c0
    int woff = 128 + ((lane & 32) << 3) + c0;
    *(bf16x4*)&gmO[(size_t)wid * 512 + woff] = outv;
}

// ---------------- conv layer 1: writes split g1 into interleaved gm ----------------
__global__ void conv1_kernel(const float* __restrict__ x, const float* __restrict__ msg1,
                             const float* __restrict__ W1r, const float* __restrict__ W1n,
                             const float* __restrict__ b1, __bf16* __restrict__ gmI) {
    int idx = blockIdx.x * 256 + threadIdx.x;
    int n = idx >> 4, c8 = (idx & 15) << 3;
    float x0 = x[n * 2], x1 = x[n * 2 + 1];
    float m0 = msg1[n * 2], m1 = msg1[n * 2 + 1];
    bf16x8 hv, lv;
#pragma unroll
    for (int e = 0; e < 8; ++e) {
        int c = c8 + e;
        float v = b1[c];
        v = fmaf(x0, W1r[c * 2], v);
        v = fmaf(x1, W1r[c * 2 + 1], v);
        v = fmaf(m0, W1n[c * 2], v);
        v = fmaf(m1, W1n[c * 2 + 1], v);
        v = v >= 0.f ? v : 0.01f * v;
        __bf16 h = (__bf16)v;
        hv[e] = h;
        lv[e] = (__bf16)(v - (float)h);
    }
    *(bf16x8*)&gmI[(size_t)n * 512 + c8] = hv;
    *(bf16x8*)&gmI[(size_t)n * 512 + 256 + c8] = lv;
}

// ---------------- merged weight prep ----------------
__global__ void prep_all(const float* __restrict__ W2r, const float* __restrict__ W2n,
                         const float* __restrict__ nW1, const float* __restrict__ nW2,
                         const float* __restrict__ eW1, const float* __restrict__ eW2,
                         __bf16* __restrict__ wcat_hi, __bf16* __restrict__ wcat_lo,
                         __bf16* __restrict__ nW1hi, __bf16* __restrict__ nW1lo,
                         __bf16* __restrict__ nW2hi, __bf16* __restrict__ nW2lo,
                         __bf16* __restrict__ eW1hi, __bf16* __restrict__ eW1lo,
                         __bf16* __restrict__ eW2hi, __bf16* __restrict__ eW2lo) {
    int i = blockIdx.x * 256 + threadIdx.x;
    float v; __bf16 *hi, *lo; int off;
    if (i < 65536) {
        int c = i >> 8, k = i & 255;
        v = (k < 128) ? W2r[c * 128 + k] : W2n[c * 128 + (k - 128)];
        hi = wcat_hi; lo = wcat_lo; off = i;
    } else if (i < 131072) {
        off = i - 65536;  v = nW1[off]; hi = nW1hi; lo = nW1lo;
    } else if (i < 262144) {
        off = i - 131072; v = nW2[off]; hi = nW2hi; lo = nW2lo;
    } else if (i < 458752) {
        off = i - 262144; v = eW1[off]; hi = eW1hi; lo = eW1lo;
    } else {
        off = i - 458752; v = eW2[off]; hi = eW2hi; lo = eW2lo;
    }
    __bf16 h = (__bf16)v;
    hi[off] = h;
    lo[off] = (__bf16)(v - (float)h);
}

// ---------------- conv2 GEMM (r9 winner, interleaved-A addressing) ----------------
// BM=64, BN=256, 4 waves, dbuf + counted vmcnt(10). A rows interleaved [hi|lo] stride 512.
template <int MODE>
__global__ __launch_bounds__(256, 2)
void conv2_gemm(const __bf16* __restrict__ A,
                const __bf16* __restrict__ whi, const __bf16* __restrict__ wlo,
                const float* __restrict__ bias,
                float* __restrict__ out, int ldo, int M,
                const int* __restrict__ aux, const int* __restrict__ aux2) {
    __shared__ __attribute__((aligned(16))) __bf16 A2[2][64 * 64];
    __shared__ __attribute__((aligned(16))) __bf16 B2[2][256 * 64];
    const int tid = threadIdx.x, lane = tid & 63, wv = tid >> 6;
    const int fr = lane & 15, kq = lane >> 4;
    const int bm = blockIdx.x * 64;

    const __bf16* asrc[2]; int adst[2];
#pragma unroll
    for (int j = 0; j < 2; ++j) {
        int a = wv * 2 + j;
        int row = a * 8 + (lane >> 3);
        int slot = (lane & 7) ^ (row & 7);
        int m = bm + row;
        long r;
        if (MODE == 2) r = (m < M) ? (long)(m < GB ? aux[m] : aux2[m - GB]) : 0;
        else           r = (m < M) ? m : (M - 1);
        asrc[j] = A + r * 512 + (slot < 4 ? 0 : 256) + (slot & 3) * 8;
        adst[j] = a * 512;
    }
    const __bf16* bsrc[8]; int bdst[8];
#pragma unroll
    for (int j = 0; j < 8; ++j) {
        int bc = wv * 8 + j;
        int col = bc * 8 + (lane >> 3);
        int slot = (lane & 7) ^ (col & 7);
        bsrc[j] = (slot < 4 ? whi : wlo) + (size_t)col * 256 + (slot & 3) * 8;
        bdst[j] = bc * 512;
    }
    int aoh[4], aol[4], boh[4], bol[4];
#pragma unroll
    for (int mt = 0; mt < 4; ++mt) {
        int row = mt * 16 + fr;
        aoh[mt] = row * 64 + ((kq       ^ (row & 7)) * 8);
        aol[mt] = row * 64 + (((kq | 4) ^ (row & 7)) * 8);
    }
#pragma unroll
    for (int nt = 0; nt < 4; ++nt) {
        int col = wv * 64 + nt * 16 + fr;
        boh[nt] = col * 64 + ((kq       ^ (col & 7)) * 8);
        bol[nt] = col * 64 + (((kq | 4) ^ (col & 7)) * 8);
    }

    f32x4 acc[4][4];
#pragma unroll
    for (int i = 0; i < 4; ++i)
#pragma unroll
        for (int j = 0; j < 4; ++j) acc[i][j] = (f32x4){0.f, 0.f, 0.f, 0.f};

#pragma unroll
    for (int j = 0; j < 2; ++j) g2l16(asrc[j], &A2[0][adst[j]]);
#pragma unroll
    for (int j = 0; j < 8; ++j) g2l16(bsrc[j], &B2[0][bdst[j]]);
#pragma unroll
    for (int j = 0; j < 2; ++j) g2l16(asrc[j] + 32, &A2[1][adst[j]]);
#pragma unroll
    for (int j = 0; j < 8; ++j) g2l16(bsrc[j] + 32, &B2[1][bdst[j]]);

#pragma unroll
    for (int t = 0; t < 8; ++t) {
        const int cur = t & 1;
        if (t < 7) asm volatile("s_waitcnt vmcnt(10)" ::: "memory");
        else       asm volatile("s_waitcnt vmcnt(0)" ::: "memory");
        __builtin_amdgcn_s_barrier();

        bf16x8 ah[4], al[4], bh[4], bl[4];
#pragma unroll
        for (int mt = 0; mt < 4; ++mt) {
            ah[mt] = *(const bf16x8*)&A2[cur][aoh[mt]];
            al[mt] = *(const bf16x8*)&A2[cur][aol[mt]];
        }
#pragma unroll
        for (int nt = 0; nt < 4; ++nt) {
            bh[nt] = *(const bf16x8*)&B2[cur][boh[nt]];
            bl[nt] = *(const bf16x8*)&B2[cur][bol[nt]];
        }
        asm volatile("s_waitcnt lgkmcnt(0)" ::: "memory");
        __builtin_amdgcn_sched_barrier(0);
        __builtin_amdgcn_s_barrier();

        if (t + 2 < 8) {
            int ks = (t + 2) * 32;
#pragma unroll
            for (int j = 0; j < 2; ++j) g2l16(asrc[j] + ks, &A2[cur][adst[j]]);
#pragma unroll
            for (int j = 0; j < 8; ++j) g2l16(bsrc[j] + ks, &B2[cur][bdst[j]]);
        }
#pragma unroll
        for (int mt = 0; mt < 4; ++mt)
#pragma unroll
            for (int nt = 0; nt < 4; ++nt) {
                acc[mt][nt] = __builtin_amdgcn_mfma_f32_16x16x32_bf16(ah[mt], bh[nt], acc[mt][nt], 0, 0, 0);
                acc[mt][nt] = __builtin_amdgcn_mfma_f32_16x16x32_bf16(ah[mt], bl[nt], acc[mt][nt], 0, 0, 0);
                acc[mt][nt] = __builtin_amdgcn_mfma_f32_16x16x32_bf16(al[mt], bh[nt], acc[mt][nt], 0, 0, 0);
            }
    }

    const int q4 = kq * 4;
    const int cb = wv * 64;

    if (MODE == 1) {
        float s0 = 0.f, s1 = 0.f, s2 = 0.f, s3 = 0.f;
        int cur2 = -1;
        float bi0 = bias[cb + 0 * 16 + fr], bi1 = bias[cb + 1 * 16 + fr];
        float bi2 = bias[cb + 2 * 16 + fr], bi3 = bias[cb + 3 * 16 + fr];
#pragma unroll
        for (int mt = 0; mt < 4; ++mt) {
#pragma unroll
            for (int j = 0; j < 4; ++j) {
                int m = bm + mt * 16 + q4 + j;
                if (m < M) {
                    float v0 = acc[mt][0][j] + bi0;
                    float v1 = acc[mt][1][j] + bi1;
                    float v2 = acc[mt][2][j] + bi2;
                    float v3 = acc[mt][3][j] + bi3;
                    v0 = v0 >= 0.f ? v0 : 0.01f * v0;
                    v1 = v1 >= 0.f ? v1 : 0.01f * v1;
                    v2 = v2 >= 0.f ? v2 : 0.01f * v2;
                    v3 = v3 >= 0.f ? v3 : 0.01f * v3;
                    int b = aux[m];
                    if (b != cur2) {
                        if (cur2 >= 0) {
                            atomicAdd(&out[(size_t)cur2 * ldo + cb + 0 * 16 + fr], s0);
                            atomicAdd(&out[(size_t)cur2 * ldo + cb + 1 * 16 + fr], s1);
                            atomicAdd(&out[(size_t)cur2 * ldo + cb + 2 * 16 + fr], s2);
                            atomicAdd(&out[(size_t)cur2 * ldo + cb + 3 * 16 + fr], s3);
                        }
                        cur2 = b; s0 = v0; s1 = v1; s2 = v2; s3 = v3;
                    } else {
                        s0 += v0; s1 += v1; s2 += v2; s3 += v3;
                    }
                }
            }
        }
        if (cur2 >= 0) {
            atomicAdd(&out[(size_t)cur2 * ldo + cb + 0 * 16 + fr], s0);
            atomicAdd(&out[(size_t)cur2 * ldo + cb + 1 * 16 + fr], s1);
            atomicAdd(&out[(size_t)cur2 * ldo + cb + 2 * 16 + fr], s2);
            atomicAdd(&out[(size_t)cur2 * ldo + cb + 3 * 16 + fr], s3);
        }
    } else {
#pragma unroll
        for (int mt = 0; mt < 4; ++mt) {
#pragma unroll
            for (int j = 0; j < 4; ++j) {
                int m = bm + mt * 16 + q4 + j;
                if (m >= M) continue;
                int orow = (m < GB) ? m : m - GB;
                int ocol = (m < GB) ? 256 : 512;
                size_t obase = (size_t)orow * ldo + ocol;
#pragma unroll
                for (int nt = 0; nt < 4; ++nt) {
                    int cc = cb + nt * 16 + fr;
                    float v = acc[mt][nt][j] + bias[cc];
                    v = v >= 0.f ? v : 0.01f * v;
                    out[obase + cc] = v;
                }
            }
        }
    }
}

// ---------------- MLP GEMM: BM=64 x BN=64 per block, wave = 16 rows x 64 cols ----------------
template <int PRESPLIT, int OSPLIT>
__global__ __launch_bounds__(256, 4)
void mlp_gemm(const float* __restrict__ Af,
              const __bf16* __restrict__ Agh, const __bf16* __restrict__ Agl, int lda,
              const __bf16* __restrict__ whi, const __bf16* __restrict__ wlo,
              const float* __restrict__ bias,
              float* __restrict__ out, __bf16* __restrict__ outh, __bf16* __restrict__ outl,
              int ldo, int M, int K, int ctiles) {
    __shared__ __bf16 Ah[64][40], Al[64][40];
    const int bm = (blockIdx.x / ctiles) * 64;
    const int bn = (blockIdx.x % ctiles) * 64;
    const int tid = threadIdx.x, lane = tid & 63, wv = tid >> 6;

    const int sar = tid >> 2;
    const int sak = (tid & 3) * 8;
    const int arow = bm + sar;
    long asrc = arow < M ? arow : M - 1;
    const float*  Arf = PRESPLIT ? nullptr : (Af + (size_t)asrc * lda);
    const __bf16* Arh = PRESPLIT ? (Agh + (size_t)asrc * lda) : nullptr;
    const __bf16* Arl = PRESPLIT ? (Agl + (size_t)asrc * lda) : nullptr;

    const int fr = lane & 15, kg = (lane >> 4) * 8;

    const __bf16* bph[4];
    const __bf16* bpl[4];
#pragma unroll
    for (int nt = 0; nt < 4; ++nt) {
        bph[nt] = whi + (size_t)(bn + nt * 16 + fr) * K + kg;
        bpl[nt] = wlo + (size_t)(bn + nt * 16 + fr) * K + kg;
    }

    f32x4 acc[4];
#pragma unroll
    for (int j = 0; j < 4; ++j) acc[j] = (f32x4){0.f, 0.f, 0.f, 0.f};

    for (int ks = 0; ks < K; ks += 32) {
        uint4 hv, lv;
        if (PRESPLIT) {
            hv = *(const uint4*)(Arh + ks + sak);
            lv = *(const uint4*)(Arl + ks + sak);
        } else {
            float4 a0 = *(const float4*)(Arf + ks + sak);
            float4 a1 = *(const float4*)(Arf + ks + sak + 4);
            float va[8] = {a0.x, a0.y, a0.z, a0.w, a1.x, a1.y, a1.z, a1.w};
            bf16x8 h8, l8;
#pragma unroll
            for (int e = 0; e < 8; ++e) {
                float v = va[e];
                __bf16 h = (__bf16)v;
                h8[e] = h;
                l8[e] = (__bf16)(v - (float)h);
            }
            hv = *(uint4*)&h8;
            lv = *(uint4*)&l8;
        }
        __syncthreads();
        *(uint4*)&Ah[sar][sak] = hv;
        *(uint4*)&Al[sar][sak] = lv;
        __syncthreads();

        bf16x8 ahf, alf, bh[4], bl[4];
        ahf = *(const bf16x8*)&Ah[wv * 16 + fr][kg];
        alf = *(const bf16x8*)&Al[wv * 16 + fr][kg];
#pragma unroll
        for (int nt = 0; nt < 4; ++nt) {
            bh[nt] = *(const bf16x8*)(bph[nt] + ks);
            bl[nt] = *(const bf16x8*)(bpl[nt] + ks);
        }
#pragma unroll
        for (int nt = 0; nt < 4; ++nt) {
            acc[nt] = __builtin_amdgcn_mfma_f32_16x16x32_bf16(ahf, bh[nt], acc[nt], 0, 0, 0);
            acc[nt] = __builtin_amdgcn_mfma_f32_16x16x32_bf16(ahf, bl[nt], acc[nt], 0, 0, 0);
            acc[nt] = __builtin_amdgcn_mfma_f32_16x16x32_bf16(alf, bh[nt], acc[nt], 0, 0, 0);
        }
    }

    const int q4 = (lane >> 4) * 4;
#pragma unroll
    for (int j = 0; j < 4; ++j) {
        int m = bm + wv * 16 + q4 + j;
        if (m >= M) continue;
        size_t obase = (size_t)m * ldo;
#pragma unroll
        for (int nt = 0; nt < 4; ++nt) {
            int cc = bn + nt * 16 + fr;
            float v = tanhf(acc[nt][j] + bias[cc]);
            if (OSPLIT) {
                __bf16 h = (__bf16)v;
                outh[obase + cc] = h;
                outl[obase + cc] = (__bf16)(v - (float)h);
            } else {
                out[obase + cc] = v;
            }
        }
    }
}

// ---------------- output head: wave per (b,o), coalesced + shfl reduce ----------------
__global__ void outhead_kernel(const float* __restrict__ h, const float* __restrict__ W,
                               const float* __restrict__ bias, float* __restrict__ yp,
                               int total, int nout) {
    int w = (blockIdx.x * 256 + threadIdx.x) >> 6;
    int lane = threadIdx.x & 63;
    if (w >= total) return;
    int b = w / nout, o = w - b * nout;
    const float4* hr = (const float4*)(h + (size_t)b * 512) + lane * 2;
    const float4* wr = (const float4*)(W + (size_t)o * 512) + lane * 2;
    float4 h0 = hr[0], h1 = hr[1], w0 = wr[0], w1 = wr[1];
    float s = h0.x * w0.x + h0.y * w0.y + h0.z * w0.z + h0.w * w0.w +
              h1.x * w1.x + h1.y * w1.y + h1.z * w1.z + h1.w * w1.w;
#pragma unroll
    for (int off = 32; off >= 1; off >>= 1) s += __shfl_down(s, off);
    if (lane == 0) yp[w] = s + bias[o];
}

// ---------------- losses ----------------
__global__ void loss_kernel(const float* __restrict__ ypx, const float* __restrict__ ypA,
                            const float* __restrict__ y_x, const float* __restrict__ y_A,
                            float* __restrict__ out) {
    int b = blockIdx.x * 256 + threadIdx.x;
    if (b >= GB) return;
#pragma unroll
    for (int j = 0; j < 2; ++j) {
        float p  = ypx[b * 4 + j];
        float a  = p * p + 1e-7f;
        float mu = ypx[b * 4 + 2 + j];
        float e  = (y_x[b * 2 + j] - mu) / a;
        out[b * 2 + j] = e * e + logf(a);
    }
    float p  = ypA[b * 2 + 0];
    float a  = p * p + 1e-7f;
    float mu = ypA[b * 2 + 1];
    float e  = (y_A[b] - mu) / a;
    out[2 * GB + b] = e * e + logf(a);
}

extern "C" void kernel_launch(void* const* d_in, const int* in_sizes, int n_in,
                              void* d_out, int out_size, void* d_ws, size_t ws_size,
                              hipStream_t stream) {
    const float* x_x     = (const float*)d_in[0];
    const float* y_x     = (const float*)d_in[1];
    const int*   ei_x    = (const int*)d_in[2];
    const int*   batch_x = (const int*)d_in[3];
    const float* x_A     = (const float*)d_in[4];
    const float* y_A     = (const float*)d_in[5];
    const int*   ei_A    = (const int*)d_in[6];
    const int*   batch_A = (const int*)d_in[7];
    const int*   idi_A   = (const int*)d_in[8];
    const int*   idj_A   = (const int*)d_in[9];
    const float* W1r = (const float*)d_in[10];
    const float* W1n = (const float*)d_in[11];
    const float* b1  = (const float*)d_in[12];
    const float* W2r = (const float*)d_in[13];
    const float* W2n = (const float*)d_in[14];
    const float* b2  = (const float*)d_in[15];
    const float* nW1 = (const float*)d_in[16];
    const float* nb1 = (const float*)d_in[17];
    const float* nW2 = (const float*)d_in[18];
    const float* nb2 = (const float*)d_in[19];
    const float* nW3 = (const float*)d_in[20];
    const float* nb3 = (const float*)d_in[21];
    const float* eW1 = (const float*)d_in[22];
    const float* eb1 = (const float*)d_in[23];
    const float* eW2 = (const float*)d_in[24];
    const float* eb2 = (const float*)d_in[25];
    const float* eW3 = (const float*)d_in[26];
    const float* eb3 = (const float*)d_in[27];

    // ---- workspace layout ----
    __bf16* gmI  = (__bf16*)d_ws;                    // GN*512 (interleaved hi|lo)
    float*  msg1 = (float*)(gmI + (size_t)GN * 512); // 2*GN*2
    float*  rgx  = msg1 + (size_t)2 * GN * 2;        // GB*256
    float*  use  = rgx  + (size_t)GB * 256;          // GB*768
    __bf16* wcat_hi = (__bf16*)(use + (size_t)GB * 768);
    __bf16* wcat_lo = wcat_hi + 65536;
    __bf16* nW1hi = wcat_lo + 65536;
    __bf16* nW1lo = nW1hi + 65536;
    __bf16* nW2hi = nW1lo + 65536;
    __bf16* nW2lo = nW2hi + 131072;
    __bf16* eW1hi = nW2lo + 131072;
    __bf16* eW1lo = eW1hi + 196608;
    __bf16* eW2hi = eW1lo + 196608;
    __bf16* eW2lo = eW2hi + 131072;
    int* rowptr = (int*)(eW2lo + 131072);            // 2*GN
    int* cursor = rowptr + 2 * GN;                   // 2*GN
    int* eidx   = cursor + 2 * GN;                   // 2*GE
    int* csum   = eidx + 2 * GE;                     // 256
    char* wend  = (char*)(csum + 256);
    // aliases into gmI region (dead after sel-GEMM):
    __bf16* h1h = gmI;
    __bf16* h1l = h1h + (size_t)GB * 256;
    float*  h2  = (float*)(h1l + (size_t)GB * 256);
    float*  ypx = h2 + (size_t)GB * 512;
    float*  ypA = ypx + (size_t)GB * 4;

    size_t need = (size_t)(wend - (char*)d_ws);
    if (ws_size < need) return;

    float* out = (float*)d_out;

    // merged weight prep
    prep_all<<<2304, 256, 0, stream>>>(W2r, W2n, nW1, nW2, eW1, eW2,
                                       wcat_hi, wcat_lo, nW1hi, nW1lo, nW2hi, nW2lo,
                                       eW1hi, eW1lo, eW2hi, eW2lo);

    // CSR + msg1 for BOTH graphs, fused
    hipMemsetAsync(rowptr, 0, (size_t)2 * GN * sizeof(int), stream);
    deg2_kernel<<<(2 * GE + 255) / 256, 256, 0, stream>>>(ei_x + GE, ei_A + GE, rowptr);
    scan1_kernel<<<2 * NCHUNK, 512, 0, stream>>>(rowptr, csum);
    scan2_kernel<<<2, 128, 0, stream>>>(csum);
    scan3_kernel<<<(2 * GN + 255) / 256, 256, 0, stream>>>(rowptr, cursor, csum);
    fill2_kernel<<<(2 * GE + 255) / 256, 256, 0, stream>>>(ei_x, ei_x + GE, ei_A, ei_A + GE,
                                                           cursor, eidx);
    msg1_kernel<<<(2 * GN + 255) / 256, 256, 0, stream>>>(x_x, x_A, rowptr, cursor, eidx, msg1);

    // zero both readout buffers in one shot (contiguous)
    hipMemsetAsync(rgx, 0, (size_t)(GB * 256 + GB * 768) * sizeof(float), stream);

    const int conv2_grid = GN / 64;                 // 3125
    const int sel_grid   = (2 * GB + 63) / 64;      // 313

    for (int g = 0; g < 2; ++g) {
        const float* x = g == 0 ? x_x : x_A;
        const int* rp  = rowptr + g * GN;
        const int* cu  = cursor + g * GN;
        const int* ei  = eidx + (size_t)g * GE;
        const int* bat = g == 0 ? batch_x : batch_A;
        const float* m1g = msg1 + (size_t)g * GN * 2;

        conv1_kernel<<<GN * 16 / 256, 256, 0, stream>>>(x, m1g, W1r, W1n, b1, gmI);
        msg2_csr_kernel<<<GN / 4, 256, 0, stream>>>(x, m1g, W1r, W1n, b1, rp, cu, ei, gmI);

        if (g == 0) {
            conv2_gemm<1><<<conv2_grid, 256, 0, stream>>>(
                gmI, wcat_hi, wcat_lo, b2, rgx, 256, GN, bat, nullptr);
        } else {
            conv2_gemm<1><<<conv2_grid, 256, 0, stream>>>(
                gmI, wcat_hi, wcat_lo, b2, use, 768, GN, bat, nullptr);
            conv2_gemm<2><<<sel_grid, 256, 0, stream>>>(
                gmI, wcat_hi, wcat_lo, b2, use, 768, 2 * GB, idi_A, idj_A);
        }
    }

    const int mlp_mt = (GB + 63) / 64;   // 157

    // node MLP (h1/h2 alias gmI region; gm dead now)
    mlp_gemm<0, 1><<<mlp_mt * 4, 256, 0, stream>>>(
        rgx, nullptr, nullptr, 256, nW1hi, nW1lo, nb1,
        nullptr, h1h, h1l, 256, GB, 256, 4);
    mlp_gemm<1, 0><<<mlp_mt * 8, 256, 0, stream>>>(
        nullptr, h1h, h1l, 256, nW2hi, nW2lo, nb2,
        h2, nullptr, nullptr, 512, GB, 256, 8);
    outhead_kernel<<<(GB * 4 * 64 + 255) / 256, 256, 0, stream>>>(h2, nW3, nb3, ypx, GB * 4, 4);

    // edge MLP
    mlp_gemm<0, 1><<<mlp_mt * 4, 256, 0, stream>>>(
        use, nullptr, nullptr, 768, eW1hi, eW1lo, eb1,
        nullptr, h1h, h1l, 256, GB, 768, 4);
    mlp_gemm<1, 0><<<mlp_mt * 8, 256, 0, stream>>>(
        nullptr, h1h, h1l, 256, eW2hi, eW2lo, eb2,
        h2, nullptr, nullptr, 512, GB, 256, 8);
    outhead_kernel<<<(GB * 2 * 64 + 255) / 256, 256, 0, stream>>>(h2, eW3, eb3, ypA, GB * 2, 2);

    loss_kernel<<<(GB + 255) / 256, 256, 0, stream>>>(ypx, ypA, y_x, y_A, out);
}

// Round 14
// 972.094 us; speedup vs baseline: 1.0609x; 1.0151x over previous
//
#include <hip/hip_runtime.h>
#include <hip/hip_bf16.h>

#define GN 200000
#define GB 10000
#define GE 600000
#define NCHUNK 98   // ceil(GN/2048)

typedef __bf16 bf16x8 __attribute__((ext_vector_type(8)));
typedef __bf16 bf16x4 __attribute__((ext_vector_type(4)));
typedef float  f32x4  __attribute__((ext_vector_type(4)));

__device__ inline float bfu2f(unsigned int u) {
    union { unsigned int i; float f; } c;
    c.i = u << 16;
    return c.f;
}

// async global->LDS, 16B per lane; lds dest = wave-uniform base + lane*16
__device__ __forceinline__ void g2l16(const void* g, void* l) {
    __builtin_amdgcn_global_load_lds(
        (const __attribute__((address_space(1))) unsigned int*)g,
        (__attribute__((address_space(3))) unsigned int*)l, 16, 0, 0);
}

// ---------------- CSR construction (both graphs fused) ----------------
__global__ void deg2_kernel(const int* __restrict__ dst0, const int* __restrict__ dst1,
                            int* __restrict__ deg) {
    int e = blockIdx.x * 256 + threadIdx.x;
    if (e >= 2 * GE) return;
    int g = e >= GE ? 1 : 0;
    int ee = e - g * GE;
    const int* d = g ? dst1 : dst0;
    atomicAdd(&deg[g * GN + d[ee]], 1);
}

__global__ void scan1_kernel(int* __restrict__ data, int* __restrict__ csum) {
    __shared__ int ls[512];
    int b = blockIdx.x, t = threadIdx.x;
    int g = b >= NCHUNK ? 1 : 0;
    int bb = b - g * NCHUNK;
    int* dp = data + g * GN;
    int base = bb * 2048 + t * 4;
    int v0 = base + 0 < GN ? dp[base + 0] : 0;
    int v1 = base + 1 < GN ? dp[base + 1] : 0;
    int v2 = base + 2 < GN ? dp[base + 2] : 0;
    int v3 = base + 3 < GN ? dp[base + 3] : 0;
    int s = v0 + v1 + v2 + v3;
    ls[t] = s;
    __syncthreads();
    for (int off = 1; off < 512; off <<= 1) {
        int x = (t >= off) ? ls[t - off] : 0;
        __syncthreads();
        ls[t] += x;
        __syncthreads();
    }
    int excl = ls[t] - s;
    if (t == 511) csum[g * 128 + bb] = ls[511];
    if (base + 0 < GN) dp[base + 0] = excl;
    if (base + 1 < GN) dp[base + 1] = excl + v0;
    if (base + 2 < GN) dp[base + 2] = excl + v0 + v1;
    if (base + 3 < GN) dp[base + 3] = excl + v0 + v1 + v2;
}

__global__ void scan2_kernel(int* __restrict__ csum) {
    __shared__ int ls[128];
    int t = threadIdx.x;
    int* cp = csum + blockIdx.x * 128;
    int v = (t < NCHUNK) ? cp[t] : 0;
    ls[t] = v;
    __syncthreads();
    for (int off = 1; off < 128; off <<= 1) {
        int x = (t >= off) ? ls[t - off] : 0;
        __syncthreads();
        ls[t] += x;
        __syncthreads();
    }
    if (t < NCHUNK) cp[t] = ls[t] - v;
}

__global__ void scan3_kernel(int* __restrict__ rowptr, int* __restrict__ cursor,
                             const int* __restrict__ csum) {
    int i = blockIdx.x * 256 + threadIdx.x;
    if (i >= 2 * GN) return;
    int g = i >= GN ? 1 : 0;
    int ii = i - g * GN;
    int v = rowptr[i] + csum[g * 128 + (ii >> 11)];
    rowptr[i] = v;
    cursor[i] = v;
}

__global__ void fill2_kernel(const int* __restrict__ src0, const int* __restrict__ dst0,
                             const int* __restrict__ src1, const int* __restrict__ dst1,
                             int* __restrict__ cursor, int* __restrict__ eidx) {
    int e = blockIdx.x * 256 + threadIdx.x;
    if (e >= 2 * GE) return;
    int g = e >= GE ? 1 : 0;
    int ee = e - g * GE;
    const int* s = g ? src1 : src0;
    const int* d = g ? dst1 : dst0;
    int p = atomicAdd(&cursor[g * GN + d[ee]], 1);
    eidx[g * GE + p] = s[ee];
}

// ---------------- msg1 + operand pack: xm[i] = {x0, x1, msg1_0, msg1_1} ----------------
__global__ void xm_kernel(const float* __restrict__ x0p, const float* __restrict__ x1p,
                          const int* __restrict__ rowptr, const int* __restrict__ cursor,
                          const int* __restrict__ eidx, float4* __restrict__ xm) {
    int i = blockIdx.x * 256 + threadIdx.x;
    if (i >= 2 * GN) return;
    int g = i >= GN ? 1 : 0;
    const float* x = g ? x1p : x0p;
    const int* ei = eidx + g * GE;
    int n = i - g * GN;
    int k = rowptr[i], k1 = cursor[i];
    float a0 = 0.f, a1 = 0.f;
    for (; k + 1 < k1; k += 2) {
        int sa = ei[k], sb = ei[k + 1];
        float2 va = *(const float2*)&x[sa * 2];
        float2 vb = *(const float2*)&x[sb * 2];
        a0 += va.x + vb.x;
        a1 += va.y + vb.y;
    }
    if (k < k1) {
        int sa = ei[k];
        float2 va = *(const float2*)&x[sa * 2];
        a0 += va.x;
        a1 += va.y;
    }
    float2 xv = *(const float2*)&x[n * 2];
    xm[i] = make_float4(xv.x, xv.y, a0, a1);
}

// ---------------- fused conv1 + msg2: wave per node ----------------
// g1[c] = lrelu(W1r[c]·x + W1n[c]·m + b1[c]) computed from xm (L2-resident, 16B/node).
// Lane owns 4 channels c0=(lane&31)*4; lanes 0-31 emit hi, 32-63 emit lo (redundant compute).
// Writes own g1 (ch 0..127) and msg2 = sum over in-edges of g1[src] (ch 128..255), into
// interleaved gmI row [hi 0..255 | lo 0..255], stride 512.
__global__ void node_kernel(const float4* __restrict__ xm,
                            const float* __restrict__ W1r, const float* __restrict__ W1n,
                            const float* __restrict__ b1,
                            const int* __restrict__ rowptr, const int* __restrict__ cursor,
                            const int* __restrict__ eidx, __bf16* __restrict__ gmI) {
    int wid = (blockIdx.x * 256 + threadIdx.x) >> 6;
    int lane = threadIdx.x & 63;
    if (wid >= GN) return;
    const int c0 = (lane & 31) * 4;
    float wr0[4], wr1[4], wn0[4], wn1[4], bb[4];
#pragma unroll
    for (int j = 0; j < 4; ++j) {
        int c = c0 + j;
        float2 wr = *(const float2*)&W1r[c * 2];
        float2 wn = *(const float2*)&W1n[c * 2];
        wr0[j] = wr.x; wr1[j] = wr.y;
        wn0[j] = wn.x; wn1[j] = wn.y;
        bb[j] = b1[c];
    }
    const int hilo = (lane & 32) << 3;   // 0 for hi lanes, 256 for lo lanes

    // own g1
    float4 me = xm[wid];
    float g[4];
#pragma unroll
    for (int j = 0; j < 4; ++j) {
        float v = bb[j];
        v = fmaf(me.x, wr0[j], v);
        v = fmaf(me.y, wr1[j], v);
        v = fmaf(me.z, wn0[j], v);
        v = fmaf(me.w, wn1[j], v);
        g[j] = v >= 0.f ? v : 0.01f * v;
    }
    bf16x4 gv;
    if (lane < 32) {
        gv = (bf16x4){(__bf16)g[0], (__bf16)g[1], (__bf16)g[2], (__bf16)g[3]};
    } else {
#pragma unroll
        for (int j = 0; j < 4; ++j) g[j] -= (float)(__bf16)g[j];
        gv = (bf16x4){(__bf16)g[0], (__bf16)g[1], (__bf16)g[2], (__bf16)g[3]};
    }
    *(bf16x4*)&gmI[(size_t)wid * 512 + hilo + c0] = gv;

    // msg2 = sum of recomputed g1[src]
    float acc[4] = {0.f, 0.f, 0.f, 0.f};
    int k = rowptr[wid], k1 = cursor[wid];
    for (; k + 1 < k1; k += 2) {
        int sa = eidx[k], sb = eidx[k + 1];
        float4 va = xm[sa];
        float4 vb = xm[sb];
#pragma unroll
        for (int j = 0; j < 4; ++j) {
            float u = bb[j];
            u = fmaf(va.x, wr0[j], u);
            u = fmaf(va.y, wr1[j], u);
            u = fmaf(va.z, wn0[j], u);
            u = fmaf(va.w, wn1[j], u);
            u = u >= 0.f ? u : 0.01f * u;
            float w = bb[j];
            w = fmaf(vb.x, wr0[j], w);
            w = fmaf(vb.y, wr1[j], w);
            w = fmaf(vb.z, wn0[j], w);
            w = fmaf(vb.w, wn1[j], w);
            w = w >= 0.f ? w : 0.01f * w;
            acc[j] += u + w;
        }
    }
    if (k < k1) {
        int sa = eidx[k];
        float4 va = xm[sa];
#pragma unroll
        for (int j = 0; j < 4; ++j) {
            float u = bb[j];
            u = fmaf(va.x, wr0[j], u);
            u = fmaf(va.y, wr1[j], u);
            u = fmaf(va.z, wn0[j], u);
            u = fmaf(va.w, wn1[j], u);
            u = u >= 0.f ? u : 0.01f * u;
            acc[j] += u;
        }
    }
    bf16x4 outv;
    if (lane < 32) {
        outv = (bf16x4){(__bf16)acc[0], (__bf16)acc[1], (__bf16)acc[2], (__bf16)acc[3]};
    } else {
#pragma unroll
        for (int j = 0; j < 4; ++j) acc[j] -= (float)(__bf16)acc[j];
        outv = (bf16x4){(__bf16)acc[0], (__bf16)acc[1], (__bf16)acc[2], (__bf16)acc[3]};
    }
    *(bf16x4*)&gmI[(size_t)wid * 512 + 128 + hilo + c0] = outv;
}

// ---------------- merged weight prep ----------------
__global__ void prep_all(const float* __restrict__ W2r, const float* __restrict__ W2n,
                         const float* __restrict__ nW1, const float* __restrict__ nW2,
                         const float* __restrict__ eW1, const float* __restrict__ eW2,
                         __bf16* __restrict__ wcat_hi, __bf16* __restrict__ wcat_lo,
                         __bf16* __restrict__ nW1hi, __bf16* __restrict__ nW1lo,
                         __bf16* __restrict__ nW2hi, __bf16* __restrict__ nW2lo,
                         __bf16* __restrict__ eW1hi, __bf16* __restrict__ eW1lo,
                         __bf16* __restrict__ eW2hi, __bf16* __restrict__ eW2lo) {
    int i = blockIdx.x * 256 + threadIdx.x;
    float v; __bf16 *hi, *lo; int off;
    if (i < 65536) {
        int c = i >> 8, k = i & 255;
        v = (k < 128) ? W2r[c * 128 + k] : W2n[c * 128 + (k - 128)];
        hi = wcat_hi; lo = wcat_lo; off = i;
    } else if (i < 131072) {
        off = i - 65536;  v = nW1[off]; hi = nW1hi; lo = nW1lo;
    } else if (i < 262144) {
        off = i - 131072; v = nW2[off]; hi = nW2hi; lo = nW2lo;
    } else if (i < 458752) {
        off = i - 262144; v = eW1[off]; hi = eW1hi; lo = eW1lo;
    } else {
        off = i - 458752; v = eW2[off]; hi = eW2hi; lo = eW2lo;
    }
    __bf16 h = (__bf16)v;
    hi[off] = h;
    lo[off] = (__bf16)(v - (float)h);
}

// ---------------- conv2 GEMM (r9 winner, interleaved-A addressing) ----------------
template <int MODE>
__global__ __launch_bounds__(256, 2)
void conv2_gemm(const __bf16* __restrict__ A,
                const __bf16* __restrict__ whi, const __bf16* __restrict__ wlo,
                const float* __restrict__ bias,
                float* __restrict__ out, int ldo, int M,
                const int* __restrict__ aux, const int* __restrict__ aux2) {
    __shared__ __attribute__((aligned(16))) __bf16 A2[2][64 * 64];
    __shared__ __attribute__((aligned(16))) __bf16 B2[2][256 * 64];
    const int tid = threadIdx.x, lane = tid & 63, wv = tid >> 6;
    const int fr = lane & 15, kq = lane >> 4;
    const int bm = blockIdx.x * 64;

    const __bf16* asrc[2]; int adst[2];
#pragma unroll
    for (int j = 0; j < 2; ++j) {
        int a = wv * 2 + j;
        int row = a * 8 + (lane >> 3);
        int slot = (lane & 7) ^ (row & 7);
        int m = bm + row;
        long r;
        if (MODE == 2) r = (m < M) ? (long)(m < GB ? aux[m] : aux2[m - GB]) : 0;
        else           r = (m < M) ? m : (M - 1);
        asrc[j] = A + r * 512 + (slot < 4 ? 0 : 256) + (slot & 3) * 8;
        adst[j] = a * 512;
    }
    const __bf16* bsrc[8]; int bdst[8];
#pragma unroll
    for (int j = 0; j < 8; ++j) {
        int bc = wv * 8 + j;
        int col = bc * 8 + (lane >> 3);
        int slot = (lane & 7) ^ (col & 7);
        bsrc[j] = (slot < 4 ? whi : wlo) + (size_t)col * 256 + (slot & 3) * 8;
        bdst[j] = bc * 512;
    }
    int aoh[4], aol[4], boh[4], bol[4];
#pragma unroll
    for (int mt = 0; mt < 4; ++mt) {
        int row = mt * 16 + fr;
        aoh[mt] = row * 64 + ((kq       ^ (row & 7)) * 8);
        aol[mt] = row * 64 + (((kq | 4) ^ (row & 7)) * 8);
    }
#pragma unroll
    for (int nt = 0; nt < 4; ++nt) {
        int col = wv * 64 + nt * 16 + fr;
        boh[nt] = col * 64 + ((kq       ^ (col & 7)) * 8);
        bol[nt] = col * 64 + (((kq | 4) ^ (col & 7)) * 8);
    }

    f32x4 acc[4][4];
#pragma unroll
    for (int i = 0; i < 4; ++i)
#pragma unroll
        for (int j = 0; j < 4; ++j) acc[i][j] = (f32x4){0.f, 0.f, 0.f, 0.f};

#pragma unroll
    for (int j = 0; j < 2; ++j) g2l16(asrc[j], &A2[0][adst[j]]);
#pragma unroll
    for (int j = 0; j < 8; ++j) g2l16(bsrc[j], &B2[0][bdst[j]]);
#pragma unroll
    for (int j = 0; j < 2; ++j) g2l16(asrc[j] + 32, &A2[1][adst[j]]);
#pragma unroll
    for (int j = 0; j < 8; ++j) g2l16(bsrc[j] + 32, &B2[1][bdst[j]]);

#pragma unroll
    for (int t = 0; t < 8; ++t) {
        const int cur = t & 1;
        if (t < 7) asm volatile("s_waitcnt vmcnt(10)" ::: "memory");
        else       asm volatile("s_waitcnt vmcnt(0)" ::: "memory");
        __builtin_amdgcn_s_barrier();

        bf16x8 ah[4], al[4], bh[4], bl[4];
#pragma unroll
        for (int mt = 0; mt < 4; ++mt) {
            ah[mt] = *(const bf16x8*)&A2[cur][aoh[mt]];
            al[mt] = *(const bf16x8*)&A2[cur][aol[mt]];
        }
#pragma unroll
        for (int nt = 0; nt < 4; ++nt) {
            bh[nt] = *(const bf16x8*)&B2[cur][boh[nt]];
            bl[nt] = *(const bf16x8*)&B2[cur][bol[nt]];
        }
        asm volatile("s_waitcnt lgkmcnt(0)" ::: "memory");
        __builtin_amdgcn_sched_barrier(0);
        __builtin_amdgcn_s_barrier();

        if (t + 2 < 8) {
            int ks = (t + 2) * 32;
#pragma unroll
            for (int j = 0; j < 2; ++j) g2l16(asrc[j] + ks, &A2[cur][adst[j]]);
#pragma unroll
            for (int j = 0; j < 8; ++j) g2l16(bsrc[j] + ks, &B2[cur][bdst[j]]);
        }
#pragma unroll
        for (int mt = 0; mt < 4; ++mt)
#pragma unroll
            for (int nt = 0; nt < 4; ++nt) {
                acc[mt][nt] = __builtin_amdgcn_mfma_f32_16x16x32_bf16(ah[mt], bh[nt], acc[mt][nt], 0, 0, 0);
                acc[mt][nt] = __builtin_amdgcn_mfma_f32_16x16x32_bf16(ah[mt], bl[nt], acc[mt][nt], 0, 0, 0);
                acc[mt][nt] = __builtin_amdgcn_mfma_f32_16x16x32_bf16(al[mt], bh[nt], acc[mt][nt], 0, 0, 0);
            }
    }

    const int q4 = kq * 4;
    const int cb = wv * 64;

    if (MODE == 1) {
        float s0 = 0.f, s1 = 0.f, s2 = 0.f, s3 = 0.f;
        int cur2 = -1;
        float bi0 = bias[cb + 0 * 16 + fr], bi1 = bias[cb + 1 * 16 + fr];
        float bi2 = bias[cb + 2 * 16 + fr], bi3 = bias[cb + 3 * 16 + fr];
#pragma unroll
        for (int mt = 0; mt < 4; ++mt) {
#pragma unroll
            for (int j = 0; j < 4; ++j) {
                int m = bm + mt * 16 + q4 + j;
                if (m < M) {
                    float v0 = acc[mt][0][j] + bi0;
                    float v1 = acc[mt][1][j] + bi1;
                    float v2 = acc[mt][2][j] + bi2;
                    float v3 = acc[mt][3][j] + bi3;
                    v0 = v0 >= 0.f ? v0 : 0.01f * v0;
                    v1 = v1 >= 0.f ? v1 : 0.01f * v1;
                    v2 = v2 >= 0.f ? v2 : 0.01f * v2;
                    v3 = v3 >= 0.f ? v3 : 0.01f * v3;
                    int b = aux[m];
                    if (b != cur2) {
                        if (cur2 >= 0) {
                            atomicAdd(&out[(size_t)cur2 * ldo + cb + 0 * 16 + fr], s0);
                            atomicAdd(&out[(size_t)cur2 * ldo + cb + 1 * 16 + fr], s1);
                            atomicAdd(&out[(size_t)cur2 * ldo + cb + 2 * 16 + fr], s2);
                            atomicAdd(&out[(size_t)cur2 * ldo + cb + 3 * 16 + fr], s3);
                        }
                        cur2 = b; s0 = v0; s1 = v1; s2 = v2; s3 = v3;
                    } else {
                        s0 += v0; s1 += v1; s2 += v2; s3 += v3;
                    }
                }
            }
        }
        if (cur2 >= 0) {
            atomicAdd(&out[(size_t)cur2 * ldo + cb + 0 * 16 + fr], s0);
            atomicAdd(&out[(size_t)cur2 * ldo + cb + 1 * 16 + fr], s1);
            atomicAdd(&out[(size_t)cur2 * ldo + cb + 2 * 16 + fr], s2);
            atomicAdd(&out[(size_t)cur2 * ldo + cb + 3 * 16 + fr], s3);
        }
    } else {
#pragma unroll
        for (int mt = 0; mt < 4; ++mt) {
#pragma unroll
            for (int j = 0; j < 4; ++j) {
                int m = bm + mt * 16 + q4 + j;
                if (m >= M) continue;
                int orow = (m < GB) ? m : m - GB;
                int ocol = (m < GB) ? 256 : 512;
                size_t obase = (size_t)orow * ldo + ocol;
#pragma unroll
                for (int nt = 0; nt < 4; ++nt) {
                    int cc = cb + nt * 16 + fr;
                    float v = acc[mt][nt][j] + bias[cc];
                    v = v >= 0.f ? v : 0.01f * v;
                    out[obase + cc] = v;
                }
            }
        }
    }
}

// ---------------- MLP GEMM: BM=64 x BN=64 per block, wave = 16 rows x 64 cols ----------------
template <int PRESPLIT, int OSPLIT>
__global__ __launch_bounds__(256, 4)
void mlp_gemm(const float* __restrict__ Af,
              const __bf16* __restrict__ Agh, const __bf16* __restrict__ Agl, int lda,
              const __bf16* __restrict__ whi, const __bf16* __restrict__ wlo,
              const float* __restrict__ bias,
              float* __restrict__ out, __bf16* __restrict__ outh, __bf16* __restrict__ outl,
              int ldo, int M, int K, int ctiles) {
    __shared__ __bf16 Ah[64][40], Al[64][40];
    const int bm = (blockIdx.x / ctiles) * 64;
    const int bn = (blockIdx.x % ctiles) * 64;
    const int tid = threadIdx.x, lane = tid & 63, wv = tid >> 6;

    const int sar = tid >> 2;
    const int sak = (tid & 3) * 8;
    const int arow = bm + sar;
    long asrc = arow < M ? arow : M - 1;
    const float*  Arf = PRESPLIT ? nullptr : (Af + (size_t)asrc * lda);
    const __bf16* Arh = PRESPLIT ? (Agh + (size_t)asrc * lda) : nullptr;
    const __bf16* Arl = PRESPLIT ? (Agl + (size_t)asrc * lda) : nullptr;

    const int fr = lane & 15, kg = (lane >> 4) * 8;

    const __bf16* bph[4];
    const __bf16* bpl[4];
#pragma unroll
    for (int nt = 0; nt < 4; ++nt) {
        bph[nt] = whi + (size_t)(bn + nt * 16 + fr) * K + kg;
        bpl[nt] = wlo + (size_t)(bn + nt * 16 + fr) * K + kg;
    }

    f32x4 acc[4];
#pragma unroll
    for (int j = 0; j < 4; ++j) acc[j] = (f32x4){0.f, 0.f, 0.f, 0.f};

    for (int ks = 0; ks < K; ks += 32) {
        uint4 hv, lv;
        if (PRESPLIT) {
            hv = *(const uint4*)(Arh + ks + sak);
            lv = *(const uint4*)(Arl + ks + sak);
        } else {
            float4 a0 = *(const float4*)(Arf + ks + sak);
            float4 a1 = *(const float4*)(Arf + ks + sak + 4);
            float va[8] = {a0.x, a0.y, a0.z, a0.w, a1.x, a1.y, a1.z, a1.w};
            bf16x8 h8, l8;
#pragma unroll
            for (int e = 0; e < 8; ++e) {
                float v = va[e];
                __bf16 h = (__bf16)v;
                h8[e] = h;
                l8[e] = (__bf16)(v - (float)h);
            }
            hv = *(uint4*)&h8;
            lv = *(uint4*)&l8;
        }
        __syncthreads();
        *(uint4*)&Ah[sar][sak] = hv;
        *(uint4*)&Al[sar][sak] = lv;
        __syncthreads();

        bf16x8 ahf, alf, bh[4], bl[4];
        ahf = *(const bf16x8*)&Ah[wv * 16 + fr][kg];
        alf = *(const bf16x8*)&Al[wv * 16 + fr][kg];
#pragma unroll
        for (int nt = 0; nt < 4; ++nt) {
            bh[nt] = *(const bf16x8*)(bph[nt] + ks);
            bl[nt] = *(const bf16x8*)(bpl[nt] + ks);
        }
#pragma unroll
        for (int nt = 0; nt < 4; ++nt) {
            acc[nt] = __builtin_amdgcn_mfma_f32_16x16x32_bf16(ahf, bh[nt], acc[nt], 0, 0, 0);
            acc[nt] = __builtin_amdgcn_mfma_f32_16x16x32_bf16(ahf, bl[nt], acc[nt], 0, 0, 0);
            acc[nt] = __builtin_amdgcn_mfma_f32_16x16x32_bf16(alf, bh[nt], acc[nt], 0, 0, 0);
        }
    }

    const int q4 = (lane >> 4) * 4;
#pragma unroll
    for (int j = 0; j < 4; ++j) {
        int m = bm + wv * 16 + q4 + j;
        if (m >= M) continue;
        size_t obase = (size_t)m * ldo;
#pragma unroll
        for (int nt = 0; nt < 4; ++nt) {
            int cc = bn + nt * 16 + fr;
            float v = tanhf(acc[nt][j] + bias[cc]);
            if (OSPLIT) {
                __bf16 h = (__bf16)v;
                outh[obase + cc] = h;
                outl[obase + cc] = (__bf16)(v - (float)h);
            } else {
                out[obase + cc] = v;
            }
        }
    }
}

// ---------------- output head: wave per (b,o), coalesced + shfl reduce ----------------
__global__ void outhead_kernel(const float* __restrict__ h, const float* __restrict__ W,
                               const float* __restrict__ bias, float* __restrict__ yp,
                               int total, int nout) {
    int w = (blockIdx.x * 256 + threadIdx.x) >> 6;
    int lane = threadIdx.x & 63;
    if (w >= total) return;
    int b = w / nout, o = w - b * nout;
    const float4* hr = (const float4*)(h + (size_t)b * 512) + lane * 2;
    const float4* wr = (const float4*)(W + (size_t)o * 512) + lane * 2;
    float4 h0 = hr[0], h1 = hr[1], w0 = wr[0], w1 = wr[1];
    float s = h0.x * w0.x + h0.y * w0.y + h0.z * w0.z + h0.w * w0.w +
              h1.x * w1.x + h1.y * w1.y + h1.z * w1.z + h1.w * w1.w;
#pragma unroll
    for (int off = 32; off >= 1; off >>= 1) s += __shfl_down(s, off);
    if (lane == 0) yp[w] = s + bias[o];
}

// ---------------- losses ----------------
__global__ void loss_kernel(const float* __restrict__ ypx, const float* __restrict__ ypA,
                            const float* __restrict__ y_x, const float* __restrict__ y_A,
                            float* __restrict__ out) {
    int b = blockIdx.x * 256 + threadIdx.x;
    if (b >= GB) return;
#pragma unroll
    for (int j = 0; j < 2; ++j) {
        float p  = ypx[b * 4 + j];
        float a  = p * p + 1e-7f;
        float mu = ypx[b * 4 + 2 + j];
        float e  = (y_x[b * 2 + j] - mu) / a;
        out[b * 2 + j] = e * e + logf(a);
    }
    float p  = ypA[b * 2 + 0];
    float a  = p * p + 1e-7f;
    float mu = ypA[b * 2 + 1];
    float e  = (y_A[b] - mu) / a;
    out[2 * GB + b] = e * e + logf(a);
}

extern "C" void kernel_launch(void* const* d_in, const int* in_sizes, int n_in,
                              void* d_out, int out_size, void* d_ws, size_t ws_size,
                              hipStream_t stream) {
    const float* x_x     = (const float*)d_in[0];
    const float* y_x     = (const float*)d_in[1];
    const int*   ei_x    = (const int*)d_in[2];
    const int*   batch_x = (const int*)d_in[3];
    const float* x_A     = (const float*)d_in[4];
    const float* y_A     = (const float*)d_in[5];
    const int*   ei_A    = (const int*)d_in[6];
    const int*   batch_A = (const int*)d_in[7];
    const int*   idi_A   = (const int*)d_in[8];
    const int*   idj_A   = (const int*)d_in[9];
    const float* W1r = (const float*)d_in[10];
    const float* W1n = (const float*)d_in[11];
    const float* b1  = (const float*)d_in[12];
    const float* W2r = (const float*)d_in[13];
    const float* W2n = (const float*)d_in[14];
    const float* b2  = (const float*)d_in[15];
    const float* nW1 = (const float*)d_in[16];
    const float* nb1 = (const float*)d_in[17];
    const float* nW2 = (const float*)d_in[18];
    const float* nb2 = (const float*)d_in[19];
    const float* nW3 = (const float*)d_in[20];
    const float* nb3 = (const float*)d_in[21];
    const float* eW1 = (const float*)d_in[22];
    const float* eb1 = (const float*)d_in[23];
    const float* eW2 = (const float*)d_in[24];
    const float* eb2 = (const float*)d_in[25];
    const float* eW3 = (const float*)d_in[26];
    const float* eb3 = (const float*)d_in[27];

    // ---- workspace layout ----
    __bf16* gmI  = (__bf16*)d_ws;                    // GN*512 (interleaved hi|lo)
    float4* xm   = (float4*)(gmI + (size_t)GN * 512);// 2*GN float4
    float*  rgx  = (float*)(xm + (size_t)2 * GN);    // GB*256
    float*  use  = rgx  + (size_t)GB * 256;          // GB*768
    __bf16* wcat_hi = (__bf16*)(use + (size_t)GB * 768);
    __bf16* wcat_lo = wcat_hi + 65536;
    __bf16* nW1hi = wcat_lo + 65536;
    __bf16* nW1lo = nW1hi + 65536;
    __bf16* nW2hi = nW1lo + 65536;
    __bf16* nW2lo = nW2hi + 131072;
    __bf16* eW1hi = nW2lo + 131072;
    __bf16* eW1lo = eW1hi + 196608;
    __bf16* eW2hi = eW1lo + 196608;
    __bf16* eW2lo = eW2hi + 131072;
    int* rowptr = (int*)(eW2lo + 131072);            // 2*GN
    int* cursor = rowptr + 2 * GN;                   // 2*GN
    int* eidx   = cursor + 2 * GN;                   // 2*GE
    int* csum   = eidx + 2 * GE;                     // 256
    char* wend  = (char*)(csum + 256);
    // aliases into gmI region (dead after sel-GEMM):
    __bf16* h1h = gmI;
    __bf16* h1l = h1h + (size_t)GB * 256;
    float*  h2  = (float*)(h1l + (size_t)GB * 256);
    float*  ypx = h2 + (size_t)GB * 512;
    float*  ypA = ypx + (size_t)GB * 4;

    size_t need = (size_t)(wend - (char*)d_ws);
    if (ws_size < need) return;

    float* out = (float*)d_out;

    // merged weight prep
    prep_all<<<2304, 256, 0, stream>>>(W2r, W2n, nW1, nW2, eW1, eW2,
                                       wcat_hi, wcat_lo, nW1hi, nW1lo, nW2hi, nW2lo,
                                       eW1hi, eW1lo, eW2hi, eW2lo);

    // CSR + xm for BOTH graphs, fused
    hipMemsetAsync(rowptr, 0, (size_t)2 * GN * sizeof(int), stream);
    deg2_kernel<<<(2 * GE + 255) / 256, 256, 0, stream>>>(ei_x + GE, ei_A + GE, rowptr);
    scan1_kernel<<<2 * NCHUNK, 512, 0, stream>>>(rowptr, csum);
    scan2_kernel<<<2, 128, 0, stream>>>(csum);
    scan3_kernel<<<(2 * GN + 255) / 256, 256, 0, stream>>>(rowptr, cursor, csum);
    fill2_kernel<<<(2 * GE + 255) / 256, 256, 0, stream>>>(ei_x, ei_x + GE, ei_A, ei_A + GE,
                                                           cursor, eidx);
    xm_kernel<<<(2 * GN + 255) / 256, 256, 0, stream>>>(x_x, x_A, rowptr, cursor, eidx, xm);

    // zero both readout buffers in one shot (contiguous)
    hipMemsetAsync(rgx, 0, (size_t)(GB * 256 + GB * 768) * sizeof(float), stream);

    const int conv2_grid = GN / 64;                 // 3125
    const int sel_grid   = (2 * GB + 63) / 64;      // 313

    for (int g = 0; g < 2; ++g) {
        const int* rp  = rowptr + g * GN;
        const int* cu  = cursor + g * GN;
        const int* ei  = eidx + (size_t)g * GE;
        const int* bat = g == 0 ? batch_x : batch_A;
        const float4* xmg = xm + (size_t)g * GN;

        node_kernel<<<GN / 4, 256, 0, stream>>>(xmg, W1r, W1n, b1, rp, cu, ei, gmI);

        if (g == 0) {
            conv2_gemm<1><<<conv2_grid, 256, 0, stream>>>(
                gmI, wcat_hi, wcat_lo, b2, rgx, 256, GN, bat, nullptr);
        } else {
            conv2_gemm<1><<<conv2_grid, 256, 0, stream>>>(
                gmI, wcat_hi, wcat_lo, b2, use, 768, GN, bat, nullptr);
            conv2_gemm<2><<<sel_grid, 256, 0, stream>>>(
                gmI, wcat_hi, wcat_lo, b2, use, 768, 2 * GB, idi_A, idj_A);
        }
    }

    const int mlp_mt = (GB + 63) / 64;   // 157

    // node MLP (h1/h2 alias gmI region; gm dead now)
    mlp_gemm<0, 1><<<mlp_mt * 4, 256, 0, stream>>>(
        rgx, nullptr, nullptr, 256, nW1hi, nW1lo, nb1,
        nullptr, h1h, h1l, 256, GB, 256, 4);
    mlp_gemm<1, 0><<<mlp_mt * 8, 256, 0, stream>>>(
        nullptr, h1h, h1l, 256, nW2hi, nW2lo, nb2,
        h2, nullptr, nullptr, 512, GB, 256, 8);
    outhead_kernel<<<(GB * 4 * 64 + 255) / 256, 256, 0, stream>>>(h2, nW3, nb3, ypx, GB * 4, 4);

    // edge MLP
    mlp_gemm<0, 1><<<mlp_mt * 4, 256, 0, stream>>>(
        use, nullptr, nullptr, 768, eW1hi, eW1lo, eb1,
        nullptr, h1h, h1l, 256, GB, 768, 4);
    mlp_gemm<1, 0><<<mlp_mt * 8, 256, 0, stream>>>(
        nullptr, h1h, h1l, 256, eW2hi, eW2lo, eb2,
        h2, nullptr, nullptr, 512, GB, 256, 8);
    outhead_kernel<<<(GB * 2 * 64 + 255) / 256, 256, 0, stream>>>(h2, eW3, eb3, ypA, GB * 2, 2);

    loss_kernel<<<(GB + 255) / 256, 256, 0, stream>>>(ypx, ypA, y_x, y_A, out);
}

// Round 15
// 958.640 us; speedup vs baseline: 1.0758x; 1.0140x over previous
//
#include <hip/hip_runtime.h>
#include <hip/hip_bf16.h>

#define GN 200000
#define GB 10000
#define GE 600000
#define NCHUNK 98   // ceil(GN/2048)

typedef __bf16 bf16x8 __attribute__((ext_vector_type(8)));
typedef __bf16 bf16x4 __attribute__((ext_vector_type(4)));
typedef float  f32x4  __attribute__((ext_vector_type(4)));

__device__ inline float bfu2f(unsigned int u) {
    union { unsigned int i; float f; } c;
    c.i = u << 16;
    return c.f;
}

// async global->LDS, 16B per lane; lds dest = wave-uniform base + lane*16
__device__ __forceinline__ void g2l16(const void* g, void* l) {
    __builtin_amdgcn_global_load_lds(
        (const __attribute__((address_space(1))) unsigned int*)g,
        (__attribute__((address_space(3))) unsigned int*)l, 16, 0, 0);
}

// ---------------- CSR construction (both graphs fused) ----------------
__global__ void deg2_kernel(const int* __restrict__ dst0, const int* __restrict__ dst1,
                            int* __restrict__ deg) {
    int e = blockIdx.x * 256 + threadIdx.x;
    if (e >= 2 * GE) return;
    int g = e >= GE ? 1 : 0;
    int ee = e - g * GE;
    const int* d = g ? dst1 : dst0;
    atomicAdd(&deg[g * GN + d[ee]], 1);
}

__global__ void scan1_kernel(int* __restrict__ data, int* __restrict__ csum) {
    __shared__ int ls[512];
    int b = blockIdx.x, t = threadIdx.x;
    int g = b >= NCHUNK ? 1 : 0;
    int bb = b - g * NCHUNK;
    int* dp = data + g * GN;
    int base = bb * 2048 + t * 4;
    int v0 = base + 0 < GN ? dp[base + 0] : 0;
    int v1 = base + 1 < GN ? dp[base + 1] : 0;
    int v2 = base + 2 < GN ? dp[base + 2] : 0;
    int v3 = base + 3 < GN ? dp[base + 3] : 0;
    int s = v0 + v1 + v2 + v3;
    ls[t] = s;
    __syncthreads();
    for (int off = 1; off < 512; off <<= 1) {
        int x = (t >= off) ? ls[t - off] : 0;
        __syncthreads();
        ls[t] += x;
        __syncthreads();
    }
    int excl = ls[t] - s;
    if (t == 511) csum[g * 128 + bb] = ls[511];
    if (base + 0 < GN) dp[base + 0] = excl;
    if (base + 1 < GN) dp[base + 1] = excl + v0;
    if (base + 2 < GN) dp[base + 2] = excl + v0 + v1;
    if (base + 3 < GN) dp[base + 3] = excl + v0 + v1 + v2;
}

__global__ void scan2_kernel(int* __restrict__ csum) {
    __shared__ int ls[128];
    int t = threadIdx.x;
    int* cp = csum + blockIdx.x * 128;
    int v = (t < NCHUNK) ? cp[t] : 0;
    ls[t] = v;
    __syncthreads();
    for (int off = 1; off < 128; off <<= 1) {
        int x = (t >= off) ? ls[t - off] : 0;
        __syncthreads();
        ls[t] += x;
        __syncthreads();
    }
    if (t < NCHUNK) cp[t] = ls[t] - v;
}

__global__ void scan3_kernel(int* __restrict__ rowptr, int* __restrict__ cursor,
                             const int* __restrict__ csum) {
    int i = blockIdx.x * 256 + threadIdx.x;
    if (i >= 2 * GN) return;
    int g = i >= GN ? 1 : 0;
    int ii = i - g * GN;
    int v = rowptr[i] + csum[g * 128 + (ii >> 11)];
    rowptr[i] = v;
    cursor[i] = v;
}

__global__ void fill2_kernel(const int* __restrict__ src0, const int* __restrict__ dst0,
                             const int* __restrict__ src1, const int* __restrict__ dst1,
                             int* __restrict__ cursor, int* __restrict__ eidx) {
    int e = blockIdx.x * 256 + threadIdx.x;
    if (e >= 2 * GE) return;
    int g = e >= GE ? 1 : 0;
    int ee = e - g * GE;
    const int* s = g ? src1 : src0;
    const int* d = g ? dst1 : dst0;
    int p = atomicAdd(&cursor[g * GN + d[ee]], 1);
    eidx[g * GE + p] = s[ee];
}

// ---------------- message passing ----------------
__global__ void msg1_kernel(const float* __restrict__ x0, const float* __restrict__ x1,
                            const int* __restrict__ rowptr, const int* __restrict__ cursor,
                            const int* __restrict__ eidx, float* __restrict__ msg1) {
    int i = blockIdx.x * 256 + threadIdx.x;
    if (i >= 2 * GN) return;
    int g = i >= GN ? 1 : 0;
    const float* x = g ? x1 : x0;
    const int* ei = eidx + g * GE;
    int k = rowptr[i], k1 = cursor[i];
    float a0 = 0.f, a1 = 0.f;
    for (; k + 1 < k1; k += 2) {
        int sa = ei[k], sb = ei[k + 1];
        float2 va = *(const float2*)&x[sa * 2];
        float2 vb = *(const float2*)&x[sb * 2];
        a0 += va.x + vb.x;
        a1 += va.y + vb.y;
    }
    if (k < k1) {
        int sa = ei[k];
        float2 va = *(const float2*)&x[sa * 2];
        a0 += va.x;
        a1 += va.y;
    }
    msg1[i * 2] = a0;
    msg1[i * 2 + 1] = a1;
}

// wave per node; gm row = [hi 256ch | lo 256ch] (stride 512). Reads g1 (ch 0..127 hi+lo)
// with ONE uint2/lane (lanes 0-31 hi, 32-63 lo), shfl-combines, writes msg2 (ch 128..255).
__global__ void msg2_csr_kernel(const __bf16* __restrict__ gmI,
                                const int* __restrict__ rowptr, const int* __restrict__ cursor,
                                const int* __restrict__ eidx, __bf16* __restrict__ gmO) {
    int wid = (blockIdx.x * 256 + threadIdx.x) >> 6;
    int lane = threadIdx.x & 63;
    if (wid >= GN) return;
    int k = rowptr[wid], k1 = cursor[wid];
    const int roff = ((lane & 32) << 3) + (lane & 31) * 4;   // hi: 0..127, lo: 256..383
    float a0 = 0.f, a1 = 0.f, a2 = 0.f, a3 = 0.f;
    for (; k + 1 < k1; k += 2) {
        int sa = eidx[k], sb = eidx[k + 1];
        uint2 va = *(const uint2*)&gmI[(size_t)sa * 512 + roff];
        uint2 vb = *(const uint2*)&gmI[(size_t)sb * 512 + roff];
        a0 += bfu2f(va.x & 0xffffu) + bfu2f(vb.x & 0xffffu);
        a1 += bfu2f(va.x >> 16)     + bfu2f(vb.x >> 16);
        a2 += bfu2f(va.y & 0xffffu) + bfu2f(vb.y & 0xffffu);
        a3 += bfu2f(va.y >> 16)     + bfu2f(vb.y >> 16);
    }
    if (k < k1) {
        int sa = eidx[k];
        uint2 va = *(const uint2*)&gmI[(size_t)sa * 512 + roff];
        a0 += bfu2f(va.x & 0xffffu);
        a1 += bfu2f(va.x >> 16);
        a2 += bfu2f(va.y & 0xffffu);
        a3 += bfu2f(va.y >> 16);
    }
    a0 += __shfl_xor(a0, 32);
    a1 += __shfl_xor(a1, 32);
    a2 += __shfl_xor(a2, 32);
    a3 += __shfl_xor(a3, 32);
    __bf16 h0 = (__bf16)a0, h1 = (__bf16)a1, h2 = (__bf16)a2, h3 = (__bf16)a3;
    bf16x4 outv;
    if (lane < 32) outv = (bf16x4){h0, h1, h2, h3};
    else outv = (bf16x4){(__bf16)(a0 - (float)h0), (__bf16)(a1 - (float)h1),
                         (__bf16)(a2 - (float)h2), (__bf16)(a3 - (float)h3)};
    int woff = 128 + ((lane & 32) << 3) + (lane & 31) * 4;
    *(bf16x4*)&gmO[(size_t)wid * 512 + woff] = outv;
}

// ---------------- conv layer 1: vectorized, writes split g1 into interleaved gm ----------------
__global__ void conv1_kernel(const float* __restrict__ x, const float* __restrict__ msg1,
                             const float* __restrict__ W1r, const float* __restrict__ W1n,
                             const float* __restrict__ b1, __bf16* __restrict__ gmI) {
    int idx = blockIdx.x * 256 + threadIdx.x;
    int n = idx >> 4, c8 = (idx & 15) << 3;
    float x0 = x[n * 2], x1 = x[n * 2 + 1];
    float m0 = msg1[n * 2], m1 = msg1[n * 2 + 1];
    bf16x8 hv, lv;
#pragma unroll
    for (int e = 0; e < 8; ++e) {
        int c = c8 + e;
        float v = b1[c];
        v = fmaf(x0, W1r[c * 2], v);
        v = fmaf(x1, W1r[c * 2 + 1], v);
        v = fmaf(m0, W1n[c * 2], v);
        v = fmaf(m1, W1n[c * 2 + 1], v);
        v = v >= 0.f ? v : 0.01f * v;
        __bf16 h = (__bf16)v;
        hv[e] = h;
        lv[e] = (__bf16)(v - (float)h);
    }
    *(bf16x8*)&gmI[(size_t)n * 512 + c8] = hv;
    *(bf16x8*)&gmI[(size_t)n * 512 + 256 + c8] = lv;
}

// ---------------- merged weight prep ----------------
__global__ void prep_all(const float* __restrict__ W2r, const float* __restrict__ W2n,
                         const float* __restrict__ nW1, const float* __restrict__ nW2,
                         const float* __restrict__ eW1, const float* __restrict__ eW2,
                         __bf16* __restrict__ wcat_hi, __bf16* __restrict__ wcat_lo,
                         __bf16* __restrict__ nW1hi, __bf16* __restrict__ nW1lo,
                         __bf16* __restrict__ nW2hi, __bf16* __restrict__ nW2lo,
                         __bf16* __restrict__ eW1hi, __bf16* __restrict__ eW1lo,
                         __bf16* __restrict__ eW2hi, __bf16* __restrict__ eW2lo) {
    int i = blockIdx.x * 256 + threadIdx.x;
    float v; __bf16 *hi, *lo; int off;
    if (i < 65536) {
        int c = i >> 8, k = i & 255;
        v = (k < 128) ? W2r[c * 128 + k] : W2n[c * 128 + (k - 128)];
        hi = wcat_hi; lo = wcat_lo; off = i;
    } else if (i < 131072) {
        off = i - 65536;  v = nW1[off]; hi = nW1hi; lo = nW1lo;
    } else if (i < 262144) {
        off = i - 131072; v = nW2[off]; hi = nW2hi; lo = nW2lo;
    } else if (i < 458752) {
        off = i - 262144; v = eW1[off]; hi = eW1hi; lo = eW1lo;
    } else {
        off = i - 458752; v = eW2[off]; hi = eW2hi; lo = eW2lo;
    }
    __bf16 h = (__bf16)v;
    hi[off] = h;
    lo[off] = (__bf16)(v - (float)h);
}

// ---------------- conv2 GEMM v9: r9 schedule, BN=128 -> 48KB LDS -> 3 blocks/CU ----------------
// BM=64 x BN=128, 4 waves (wave = 64 rows x 32 cols, acc[4][2]). ctiles=2.
// Same dbuf + counted-vmcnt schedule and swizzle as the r9 winner; only BN shrunk.
// A rows interleaved [hi|lo] stride 512. Stage = 6 g2l16/thread; steady vmcnt(6).
template <int MODE>
__global__ __launch_bounds__(256, 3)
void conv2_gemm(const __bf16* __restrict__ A,
                const __bf16* __restrict__ whi, const __bf16* __restrict__ wlo,
                const float* __restrict__ bias,
                float* __restrict__ out, int ldo, int M,
                const int* __restrict__ aux, const int* __restrict__ aux2) {
    __shared__ __attribute__((aligned(16))) __bf16 A2[2][64 * 64];    // 2x8KB
    __shared__ __attribute__((aligned(16))) __bf16 B2[2][128 * 64];   // 2x16KB
    const int tid = threadIdx.x, lane = tid & 63, wv = tid >> 6;
    const int fr = lane & 15, kq = lane >> 4;
    const int bm = (blockIdx.x >> 1) * 64;
    const int bn = (blockIdx.x & 1) * 128;

    const __bf16* asrc[2]; int adst[2];
#pragma unroll
    for (int j = 0; j < 2; ++j) {
        int a = wv * 2 + j;
        int row = a * 8 + (lane >> 3);
        int slot = (lane & 7) ^ (row & 7);
        int m = bm + row;
        long r;
        if (MODE == 2) r = (m < M) ? (long)(m < GB ? aux[m] : aux2[m - GB]) : 0;
        else           r = (m < M) ? m : (M - 1);
        asrc[j] = A + r * 512 + (slot < 4 ? 0 : 256) + (slot & 3) * 8;
        adst[j] = a * 512;
    }
    const __bf16* bsrc[4]; int bdst[4];
#pragma unroll
    for (int j = 0; j < 4; ++j) {
        int bc = wv * 4 + j;                 // 0..15 -> cols bc*8..bc*8+7 (local 0..127)
        int col = bc * 8 + (lane >> 3);
        int slot = (lane & 7) ^ (col & 7);
        bsrc[j] = (slot < 4 ? whi : wlo) + (size_t)(bn + col) * 256 + (slot & 3) * 8;
        bdst[j] = bc * 512;
    }
    int aoh[4], aol[4], boh[2], bol[2];
#pragma unroll
    for (int mt = 0; mt < 4; ++mt) {
        int row = mt * 16 + fr;
        aoh[mt] = row * 64 + ((kq       ^ (row & 7)) * 8);
        aol[mt] = row * 64 + (((kq | 4) ^ (row & 7)) * 8);
    }
#pragma unroll
    for (int nt = 0; nt < 2; ++nt) {
        int col = wv * 32 + nt * 16 + fr;    // local col 0..127
        boh[nt] = col * 64 + ((kq       ^ (col & 7)) * 8);
        bol[nt] = col * 64 + (((kq | 4) ^ (col & 7)) * 8);
    }

    f32x4 acc[4][2];
#pragma unroll
    for (int i = 0; i < 4; ++i)
#pragma unroll
        for (int j = 0; j < 2; ++j) acc[i][j] = (f32x4){0.f, 0.f, 0.f, 0.f};

#pragma unroll
    for (int j = 0; j < 2; ++j) g2l16(asrc[j], &A2[0][adst[j]]);
#pragma unroll
    for (int j = 0; j < 4; ++j) g2l16(bsrc[j], &B2[0][bdst[j]]);
#pragma unroll
    for (int j = 0; j < 2; ++j) g2l16(asrc[j] + 32, &A2[1][adst[j]]);
#pragma unroll
    for (int j = 0; j < 4; ++j) g2l16(bsrc[j] + 32, &B2[1][bdst[j]]);

#pragma unroll
    for (int t = 0; t < 8; ++t) {
        const int cur = t & 1;
        if (t < 7) asm volatile("s_waitcnt vmcnt(6)" ::: "memory");
        else       asm volatile("s_waitcnt vmcnt(0)" ::: "memory");
        __builtin_amdgcn_s_barrier();

        bf16x8 ah[4], al[4], bh[2], bl[2];
#pragma unroll
        for (int mt = 0; mt < 4; ++mt) {
            ah[mt] = *(const bf16x8*)&A2[cur][aoh[mt]];
            al[mt] = *(const bf16x8*)&A2[cur][aol[mt]];
        }
#pragma unroll
        for (int nt = 0; nt < 2; ++nt) {
            bh[nt] = *(const bf16x8*)&B2[cur][boh[nt]];
            bl[nt] = *(const bf16x8*)&B2[cur][bol[nt]];
        }
        asm volatile("s_waitcnt lgkmcnt(0)" ::: "memory");
        __builtin_amdgcn_sched_barrier(0);
        __builtin_amdgcn_s_barrier();

        if (t + 2 < 8) {
            int ks = (t + 2) * 32;
#pragma unroll
            for (int j = 0; j < 2; ++j) g2l16(asrc[j] + ks, &A2[cur][adst[j]]);
#pragma unroll
            for (int j = 0; j < 4; ++j) g2l16(bsrc[j] + ks, &B2[cur][bdst[j]]);
        }
#pragma unroll
        for (int mt = 0; mt < 4; ++mt)
#pragma unroll
            for (int nt = 0; nt < 2; ++nt) {
                acc[mt][nt] = __builtin_amdgcn_mfma_f32_16x16x32_bf16(ah[mt], bh[nt], acc[mt][nt], 0, 0, 0);
                acc[mt][nt] = __builtin_amdgcn_mfma_f32_16x16x32_bf16(ah[mt], bl[nt], acc[mt][nt], 0, 0, 0);
                acc[mt][nt] = __builtin_amdgcn_mfma_f32_16x16x32_bf16(al[mt], bh[nt], acc[mt][nt], 0, 0, 0);
            }
    }

    const int q4 = kq * 4;
    const int cb = bn + wv * 32;

    if (MODE == 1) {
        float s0 = 0.f, s1 = 0.f;
        int cur2 = -1;
        float bi0 = bias[cb + fr], bi1 = bias[cb + 16 + fr];
#pragma unroll
        for (int mt = 0; mt < 4; ++mt) {
#pragma unroll
            for (int j = 0; j < 4; ++j) {
                int m = bm + mt * 16 + q4 + j;
                if (m < M) {
                    float v0 = acc[mt][0][j] + bi0;
                    float v1 = acc[mt][1][j] + bi1;
                    v0 = v0 >= 0.f ? v0 : 0.01f * v0;
                    v1 = v1 >= 0.f ? v1 : 0.01f * v1;
                    int b = aux[m];
                    if (b != cur2) {
                        if (cur2 >= 0) {
                            atomicAdd(&out[(size_t)cur2 * ldo + cb + fr], s0);
                            atomicAdd(&out[(size_t)cur2 * ldo + cb + 16 + fr], s1);
                        }
                        cur2 = b; s0 = v0; s1 = v1;
                    } else {
                        s0 += v0; s1 += v1;
                    }
                }
            }
        }
        if (cur2 >= 0) {
            atomicAdd(&out[(size_t)cur2 * ldo + cb + fr], s0);
            atomicAdd(&out[(size_t)cur2 * ldo + cb + 16 + fr], s1);
        }
    } else {
#pragma unroll
        for (int mt = 0; mt < 4; ++mt) {
#pragma unroll
            for (int j = 0; j < 4; ++j) {
                int m = bm + mt * 16 + q4 + j;
                if (m >= M) continue;
                int orow = (m < GB) ? m : m - GB;
                int ocol = (m < GB) ? 256 : 512;
                size_t obase = (size_t)orow * ldo + ocol;
#pragma unroll
                for (int nt = 0; nt < 2; ++nt) {
                    int cc = cb + nt * 16 + fr;
                    float v = acc[mt][nt][j] + bias[cc];
                    v = v >= 0.f ? v : 0.01f * v;
                    out[obase + cc] = v;
                }
            }
        }
    }
}

// ---------------- MLP GEMM: BM=64 x BN=64 per block, wave = 16 rows x 64 cols ----------------
template <int PRESPLIT, int OSPLIT>
__global__ __launch_bounds__(256, 4)
void mlp_gemm(const float* __restrict__ Af,
              const __bf16* __restrict__ Agh, const __bf16* __restrict__ Agl, int lda,
              const __bf16* __restrict__ whi, const __bf16* __restrict__ wlo,
              const float* __restrict__ bias,
              float* __restrict__ out, __bf16* __restrict__ outh, __bf16* __restrict__ outl,
              int ldo, int M, int K, int ctiles) {
    __shared__ __bf16 Ah[64][40], Al[64][40];
    const int bm = (blockIdx.x / ctiles) * 64;
    const int bn = (blockIdx.x % ctiles) * 64;
    const int tid = threadIdx.x, lane = tid & 63, wv = tid >> 6;

    const int sar = tid >> 2;
    const int sak = (tid & 3) * 8;
    const int arow = bm + sar;
    long asrc = arow < M ? arow : M - 1;
    const float*  Arf = PRESPLIT ? nullptr : (Af + (size_t)asrc * lda);
    const __bf16* Arh = PRESPLIT ? (Agh + (size_t)asrc * lda) : nullptr;
    const __bf16* Arl = PRESPLIT ? (Agl + (size_t)asrc * lda) : nullptr;

    const int fr = lane & 15, kg = (lane >> 4) * 8;

    const __bf16* bph[4];
    const __bf16* bpl[4];
#pragma unroll
    for (int nt = 0; nt < 4; ++nt) {
        bph[nt] = whi + (size_t)(bn + nt * 16 + fr) * K + kg;
        bpl[nt] = wlo + (size_t)(bn + nt * 16 + fr) * K + kg;
    }

    f32x4 acc[4];
#pragma unroll
    for (int j = 0; j < 4; ++j) acc[j] = (f32x4){0.f, 0.f, 0.f, 0.f};

    for (int ks = 0; ks < K; ks += 32) {
        uint4 hv, lv;
        if (PRESPLIT) {
            hv = *(const uint4*)(Arh + ks + sak);
            lv = *(const uint4*)(Arl + ks + sak);
        } else {
            float4 a0 = *(const float4*)(Arf + ks + sak);
            float4 a1 = *(const float4*)(Arf + ks + sak + 4);
            float va[8] = {a0.x, a0.y, a0.z, a0.w, a1.x, a1.y, a1.z, a1.w};
            bf16x8 h8, l8;
#pragma unroll
            for (int e = 0; e < 8; ++e) {
                float v = va[e];
                __bf16 h = (__bf16)v;
                h8[e] = h;
                l8[e] = (__bf16)(v - (float)h);
            }
            hv = *(uint4*)&h8;
            lv = *(uint4*)&l8;
        }
        __syncthreads();
        *(uint4*)&Ah[sar][sak] = hv;
        *(uint4*)&Al[sar][sak] = lv;
        __syncthreads();

        bf16x8 ahf, alf, bh[4], bl[4];
        ahf = *(const bf16x8*)&Ah[wv * 16 + fr][kg];
        alf = *(const bf16x8*)&Al[wv * 16 + fr][kg];
#pragma unroll
        for (int nt = 0; nt < 4; ++nt) {
            bh[nt] = *(const bf16x8*)(bph[nt] + ks);
            bl[nt] = *(const bf16x8*)(bpl[nt] + ks);
        }
#pragma unroll
        for (int nt = 0; nt < 4; ++nt) {
            acc[nt] = __builtin_amdgcn_mfma_f32_16x16x32_bf16(ahf, bh[nt], acc[nt], 0, 0, 0);
            acc[nt] = __builtin_amdgcn_mfma_f32_16x16x32_bf16(ahf, bl[nt], acc[nt], 0, 0, 0);
            acc[nt] = __builtin_amdgcn_mfma_f32_16x16x32_bf16(alf, bh[nt], acc[nt], 0, 0, 0);
        }
    }

    const int q4 = (lane >> 4) * 4;
#pragma unroll
    for (int j = 0; j < 4; ++j) {
        int m = bm + wv * 16 + q4 + j;
        if (m >= M) continue;
        size_t obase = (size_t)m * ldo;
#pragma unroll
        for (int nt = 0; nt < 4; ++nt) {
            int cc = bn + nt * 16 + fr;
            float v = tanhf(acc[nt][j] + bias[cc]);
            if (OSPLIT) {
                __bf16 h = (__bf16)v;
                outh[obase + cc] = h;
                outl[obase + cc] = (__bf16)(v - (float)h);
            } else {
                out[obase + cc] = v;
            }
        }
    }
}

// ---------------- output head: wave per (b,o), coalesced + shfl reduce ----------------
__global__ void outhead_kernel(const float* __restrict__ h, const float* __restrict__ W,
                               const float* __restrict__ bias, float* __restrict__ yp,
                               int total, int nout) {
    int w = (blockIdx.x * 256 + threadIdx.x) >> 6;
    int lane = threadIdx.x & 63;
    if (w >= total) return;
    int b = w / nout, o = w - b * nout;
    const float4* hr = (const float4*)(h + (size_t)b * 512) + lane * 2;
    const float4* wr = (const float4*)(W + (size_t)o * 512) + lane * 2;
    float4 h0 = hr[0], h1 = hr[1], w0 = wr[0], w1 = wr[1];
    float s = h0.x * w0.x + h0.y * w0.y + h0.z * w0.z + h0.w * w0.w +
              h1.x * w1.x + h1.y * w1.y + h1.z * w1.z + h1.w * w1.w;
#pragma unroll
    for (int off = 32; off >= 1; off >>= 1) s += __shfl_down(s, off);
    if (lane == 0) yp[w] = s + bias[o];
}

// ---------------- losses ----------------
__global__ void loss_kernel(const float* __restrict__ ypx, const float* __restrict__ ypA,
                            const float* __restrict__ y_x, const float* __restrict__ y_A,
                            float* __restrict__ out) {
    int b = blockIdx.x * 256 + threadIdx.x;
    if (b >= GB) return;
#pragma unroll
    for (int j = 0; j < 2; ++j) {
        float p  = ypx[b * 4 + j];
        float a  = p * p + 1e-7f;
        float mu = ypx[b * 4 + 2 + j];
        float e  = (y_x[b * 2 + j] - mu) / a;
        out[b * 2 + j] = e * e + logf(a);
    }
    float p  = ypA[b * 2 + 0];
    float a  = p * p + 1e-7f;
    float mu = ypA[b * 2 + 1];
    float e  = (y_A[b] - mu) / a;
    out[2 * GB + b] = e * e + logf(a);
}

extern "C" void kernel_launch(void* const* d_in, const int* in_sizes, int n_in,
                              void* d_out, int out_size, void* d_ws, size_t ws_size,
                              hipStream_t stream) {
    const float* x_x     = (const float*)d_in[0];
    const float* y_x     = (const float*)d_in[1];
    const int*   ei_x    = (const int*)d_in[2];
    const int*   batch_x = (const int*)d_in[3];
    const float* x_A     = (const float*)d_in[4];
    const float* y_A     = (const float*)d_in[5];
    const int*   ei_A    = (const int*)d_in[6];
    const int*   batch_A = (const int*)d_in[7];
    const int*   idi_A   = (const int*)d_in[8];
    const int*   idj_A   = (const int*)d_in[9];
    const float* W1r = (const float*)d_in[10];
    const float* W1n = (const float*)d_in[11];
    const float* b1  = (const float*)d_in[12];
    const float* W2r = (const float*)d_in[13];
    const float* W2n = (const float*)d_in[14];
    const float* b2  = (const float*)d_in[15];
    const float* nW1 = (const float*)d_in[16];
    const float* nb1 = (const float*)d_in[17];
    const float* nW2 = (const float*)d_in[18];
    const float* nb2 = (const float*)d_in[19];
    const float* nW3 = (const float*)d_in[20];
    const float* nb3 = (const float*)d_in[21];
    const float* eW1 = (const float*)d_in[22];
    const float* eb1 = (const float*)d_in[23];
    const float* eW2 = (const float*)d_in[24];
    const float* eb2 = (const float*)d_in[25];
    const float* eW3 = (const float*)d_in[26];
    const float* eb3 = (const float*)d_in[27];

    // ---- workspace layout ----
    __bf16* gmI  = (__bf16*)d_ws;                    // GN*512 (interleaved hi|lo)
    float*  msg1 = (float*)(gmI + (size_t)GN * 512); // 2*GN*2
    float*  rgx  = msg1 + (size_t)2 * GN * 2;        // GB*256
    float*  use  = rgx  + (size_t)GB * 256;          // GB*768
    __bf16* wcat_hi = (__bf16*)(use + (size_t)GB * 768);
    __bf16* wcat_lo = wcat_hi + 65536;
    __bf16* nW1hi = wcat_lo + 65536;
    __bf16* nW1lo = nW1hi + 65536;
    __bf16* nW2hi = nW1lo + 65536;
    __bf16* nW2lo = nW2hi + 131072;
    __bf16* eW1hi = nW2lo + 131072;
    __bf16* eW1lo = eW1hi + 196608;
    __bf16* eW2hi = eW1lo + 196608;
    __bf16* eW2lo = eW2hi + 131072;
    int* rowptr = (int*)(eW2lo + 131072);            // 2*GN
    int* cursor = rowptr + 2 * GN;                   // 2*GN
    int* eidx   = cursor + 2 * GN;                   // 2*GE
    int* csum   = eidx + 2 * GE;                     // 256
    char* wend  = (char*)(csum + 256);
    // aliases into gmI region (dead after sel-GEMM):
    __bf16* h1h = gmI;
    __bf16* h1l = h1h + (size_t)GB * 256;
    float*  h2  = (float*)(h1l + (size_t)GB * 256);
    float*  ypx = h2 + (size_t)GB * 512;
    float*  ypA = ypx + (size_t)GB * 4;

    size_t need = (size_t)(wend - (char*)d_ws);
    if (ws_size < need) return;

    float* out = (float*)d_out;

    // merged weight prep
    prep_all<<<2304, 256, 0, stream>>>(W2r, W2n, nW1, nW2, eW1, eW2,
                                       wcat_hi, wcat_lo, nW1hi, nW1lo, nW2hi, nW2lo,
                                       eW1hi, eW1lo, eW2hi, eW2lo);

    // CSR + msg1 for BOTH graphs, fused
    hipMemsetAsync(rowptr, 0, (size_t)2 * GN * sizeof(int), stream);
    deg2_kernel<<<(2 * GE + 255) / 256, 256, 0, stream>>>(ei_x + GE, ei_A + GE, rowptr);
    scan1_kernel<<<2 * NCHUNK, 512, 0, stream>>>(rowptr, csum);
    scan2_kernel<<<2, 128, 0, stream>>>(csum);
    scan3_kernel<<<(2 * GN + 255) / 256, 256, 0, stream>>>(rowptr, cursor, csum);
    fill2_kernel<<<(2 * GE + 255) / 256, 256, 0, stream>>>(ei_x, ei_x + GE, ei_A, ei_A + GE,
                                                           cursor, eidx);
    msg1_kernel<<<(2 * GN + 255) / 256, 256, 0, stream>>>(x_x, x_A, rowptr, cursor, eidx, msg1);

    // zero both readout buffers in one shot (contiguous)
    hipMemsetAsync(rgx, 0, (size_t)(GB * 256 + GB * 768) * sizeof(float), stream);

    const int conv2_grid = (GN / 64) * 2;           // 6250 (row-tiles x 2 col-tiles)
    const int sel_grid   = ((2 * GB + 63) / 64) * 2;

    for (int g = 0; g < 2; ++g) {
        const float* x = g == 0 ? x_x : x_A;
        const int* rp  = rowptr + g * GN;
        const int* cu  = cursor + g * GN;
        const int* ei  = eidx + (size_t)g * GE;
        const int* bat = g == 0 ? batch_x : batch_A;

        conv1_kernel<<<GN * 16 / 256, 256, 0, stream>>>(x, msg1 + (size_t)g * GN * 2,
                                                        W1r, W1n, b1, gmI);
        msg2_csr_kernel<<<GN / 4, 256, 0, stream>>>(gmI, rp, cu, ei, gmI);

        if (g == 0) {
            conv2_gemm<1><<<conv2_grid, 256, 0, stream>>>(
                gmI, wcat_hi, wcat_lo, b2, rgx, 256, GN, bat, nullptr);
        } else {
            conv2_gemm<1><<<conv2_grid, 256, 0, stream>>>(
                gmI, wcat_hi, wcat_lo, b2, use, 768, GN, bat, nullptr);
            conv2_gemm<2><<<sel_grid, 256, 0, stream>>>(
                gmI, wcat_hi, wcat_lo, b2, use, 768, 2 * GB, idi_A, idj_A);
        }
    }

    const int mlp_mt = (GB + 63) / 64;   // 157

    // node MLP (h1/h2 alias gmI region; gm dead now)
    mlp_gemm<0, 1><<<mlp_mt * 4, 256, 0, stream>>>(
        rgx, nullptr, nullptr, 256, nW1hi, nW1lo, nb1,
        nullptr, h1h, h1l, 256, GB, 256, 4);
    mlp_gemm<1, 0><<<mlp_mt * 8, 256, 0, stream>>>(
        nullptr, h1h, h1l, 256, nW2hi, nW2lo, nb2,
        h2, nullptr, nullptr, 512, GB, 256, 8);
    outhead_kernel<<<(GB * 4 * 64 + 255) / 256, 256, 0, stream>>>(h2, nW3, nb3, ypx, GB * 4, 4);

    // edge MLP
    mlp_gemm<0, 1><<<mlp_mt * 4, 256, 0, stream>>>(
        use, nullptr, nullptr, 768, eW1hi, eW1lo, eb1,
        nullptr, h1h, h1l, 256, GB, 768, 4);
    mlp_gemm<1, 0><<<mlp_mt * 8, 256, 0, stream>>>(
        nullptr, h1h, h1l, 256, eW2hi, eW2lo, eb2,
        h2, nullptr, nullptr, 512, GB, 256, 8);
    outhead_kernel<<<(GB * 2 * 64 + 255) / 256, 256, 0, stream>>>(h2, eW3, eb3, ypA, GB * 2, 2);

    loss_kernel<<<(GB + 255) / 256, 256, 0, stream>>>(ypx, ypA, y_x, y_A, out);
}

// Round 16
// 929.955 us; speedup vs baseline: 1.1090x; 1.0308x over previous
//
#include <hip/hip_runtime.h>
#include <hip/hip_bf16.h>

#define GN 200000
#define GB 10000
#define GE 600000
#define NCHUNK 98   // ceil(GN/2048)

typedef __bf16 bf16x8 __attribute__((ext_vector_type(8)));
typedef __bf16 bf16x4 __attribute__((ext_vector_type(4)));
typedef float  f32x4  __attribute__((ext_vector_type(4)));

__device__ inline float bfu2f(unsigned int u) {
    union { unsigned int i; float f; } c;
    c.i = u << 16;
    return c.f;
}

// async global->LDS, 16B per lane; lds dest = wave-uniform base + lane*16
__device__ __forceinline__ void g2l16(const void* g, void* l) {
    __builtin_amdgcn_global_load_lds(
        (const __attribute__((address_space(1))) unsigned int*)g,
        (__attribute__((address_space(3))) unsigned int*)l, 16, 0, 0);
}

// ---------------- CSR construction (both graphs fused) ----------------
__global__ void deg2_kernel(const int* __restrict__ dst0, const int* __restrict__ dst1,
                            int* __restrict__ deg) {
    int e = blockIdx.x * 256 + threadIdx.x;
    if (e >= 2 * GE) return;
    int g = e >= GE ? 1 : 0;
    int ee = e - g * GE;
    const int* d = g ? dst1 : dst0;
    atomicAdd(&deg[g * GN + d[ee]], 1);
}

__global__ void scan1_kernel(int* __restrict__ data, int* __restrict__ csum) {
    __shared__ int ls[512];
    int b = blockIdx.x, t = threadIdx.x;
    int g = b >= NCHUNK ? 1 : 0;
    int bb = b - g * NCHUNK;
    int* dp = data + g * GN;
    int base = bb * 2048 + t * 4;
    int v0 = base + 0 < GN ? dp[base + 0] : 0;
    int v1 = base + 1 < GN ? dp[base + 1] : 0;
    int v2 = base + 2 < GN ? dp[base + 2] : 0;
    int v3 = base + 3 < GN ? dp[base + 3] : 0;
    int s = v0 + v1 + v2 + v3;
    ls[t] = s;
    __syncthreads();
    for (int off = 1; off < 512; off <<= 1) {
        int x = (t >= off) ? ls[t - off] : 0;
        __syncthreads();
        ls[t] += x;
        __syncthreads();
    }
    int excl = ls[t] - s;
    if (t == 511) csum[g * 128 + bb] = ls[511];
    if (base + 0 < GN) dp[base + 0] = excl;
    if (base + 1 < GN) dp[base + 1] = excl + v0;
    if (base + 2 < GN) dp[base + 2] = excl + v0 + v1;
    if (base + 3 < GN) dp[base + 3] = excl + v0 + v1 + v2;
}

__global__ void scan2_kernel(int* __restrict__ csum) {
    __shared__ int ls[128];
    int t = threadIdx.x;
    int* cp = csum + blockIdx.x * 128;
    int v = (t < NCHUNK) ? cp[t] : 0;
    ls[t] = v;
    __syncthreads();
    for (int off = 1; off < 128; off <<= 1) {
        int x = (t >= off) ? ls[t - off] : 0;
        __syncthreads();
        ls[t] += x;
        __syncthreads();
    }
    if (t < NCHUNK) cp[t] = ls[t] - v;
}

__global__ void scan3_kernel(int* __restrict__ rowptr, int* __restrict__ cursor,
                             const int* __restrict__ csum) {
    int i = blockIdx.x * 256 + threadIdx.x;
    if (i >= 2 * GN) return;
    int g = i >= GN ? 1 : 0;
    int ii = i - g * GN;
    int v = rowptr[i] + csum[g * 128 + (ii >> 11)];
    rowptr[i] = v;
    cursor[i] = v;
}

__global__ void fill2_kernel(const int* __restrict__ src0, const int* __restrict__ dst0,
                             const int* __restrict__ src1, const int* __restrict__ dst1,
                             int* __restrict__ cursor, int* __restrict__ eidx) {
    int e = blockIdx.x * 256 + threadIdx.x;
    if (e >= 2 * GE) return;
    int g = e >= GE ? 1 : 0;
    int ee = e - g * GE;
    const int* s = g ? src1 : src0;
    const int* d = g ? dst1 : dst0;
    int p = atomicAdd(&cursor[g * GN + d[ee]], 1);
    eidx[g * GE + p] = s[ee];
}

// ---------------- message passing ----------------
__global__ void msg1_kernel(const float* __restrict__ x0, const float* __restrict__ x1,
                            const int* __restrict__ rowptr, const int* __restrict__ cursor,
                            const int* __restrict__ eidx, float* __restrict__ msg1) {
    int i = blockIdx.x * 256 + threadIdx.x;
    if (i >= 2 * GN) return;
    int g = i >= GN ? 1 : 0;
    const float* x = g ? x1 : x0;
    const int* ei = eidx + g * GE;
    int k = rowptr[i], k1 = cursor[i];
    float a0 = 0.f, a1 = 0.f;
    for (; k + 1 < k1; k += 2) {
        int sa = ei[k], sb = ei[k + 1];
        float2 va = *(const float2*)&x[sa * 2];
        float2 vb = *(const float2*)&x[sb * 2];
        a0 += va.x + vb.x;
        a1 += va.y + vb.y;
    }
    if (k < k1) {
        int sa = ei[k];
        float2 va = *(const float2*)&x[sa * 2];
        a0 += va.x;
        a1 += va.y;
    }
    msg1[i * 2] = a0;
    msg1[i * 2 + 1] = a1;
}

// wave per node; gm row = [hi 256ch | lo 256ch] (stride 512). Reads g1 (ch 0..127 hi+lo)
// with ONE uint2/lane (lanes 0-31 hi, 32-63 lo), shfl-combines, writes msg2 (ch 128..255).
__global__ void msg2_csr_kernel(const __bf16* __restrict__ gmI,
                                const int* __restrict__ rowptr, const int* __restrict__ cursor,
                                const int* __restrict__ eidx, __bf16* __restrict__ gmO) {
    int wid = (blockIdx.x * 256 + threadIdx.x) >> 6;
    int lane = threadIdx.x & 63;
    if (wid >= GN) return;
    int k = rowptr[wid], k1 = cursor[wid];
    const int roff = ((lane & 32) << 3) + (lane & 31) * 4;   // hi: 0..127, lo: 256..383
    float a0 = 0.f, a1 = 0.f, a2 = 0.f, a3 = 0.f;
    for (; k + 1 < k1; k += 2) {
        int sa = eidx[k], sb = eidx[k + 1];
        uint2 va = *(const uint2*)&gmI[(size_t)sa * 512 + roff];
        uint2 vb = *(const uint2*)&gmI[(size_t)sb * 512 + roff];
        a0 += bfu2f(va.x & 0xffffu) + bfu2f(vb.x & 0xffffu);
        a1 += bfu2f(va.x >> 16)     + bfu2f(vb.x >> 16);
        a2 += bfu2f(va.y & 0xffffu) + bfu2f(vb.y & 0xffffu);
        a3 += bfu2f(va.y >> 16)     + bfu2f(vb.y >> 16);
    }
    if (k < k1) {
        int sa = eidx[k];
        uint2 va = *(const uint2*)&gmI[(size_t)sa * 512 + roff];
        a0 += bfu2f(va.x & 0xffffu);
        a1 += bfu2f(va.x >> 16);
        a2 += bfu2f(va.y & 0xffffu);
        a3 += bfu2f(va.y >> 16);
    }
    a0 += __shfl_xor(a0, 32);
    a1 += __shfl_xor(a1, 32);
    a2 += __shfl_xor(a2, 32);
    a3 += __shfl_xor(a3, 32);
    __bf16 h0 = (__bf16)a0, h1 = (__bf16)a1, h2 = (__bf16)a2, h3 = (__bf16)a3;
    bf16x4 outv;
    if (lane < 32) outv = (bf16x4){h0, h1, h2, h3};
    else outv = (bf16x4){(__bf16)(a0 - (float)h0), (__bf16)(a1 - (float)h1),
                         (__bf16)(a2 - (float)h2), (__bf16)(a3 - (float)h3)};
    int woff = 128 + ((lane & 32) << 3) + (lane & 31) * 4;
    *(bf16x4*)&gmO[(size_t)wid * 512 + woff] = outv;
}

// ---------------- conv layer 1: vectorized, writes split g1 into interleaved gm ----------------
__global__ void conv1_kernel(const float* __restrict__ x, const float* __restrict__ msg1,
                             const float* __restrict__ W1r, const float* __restrict__ W1n,
                             const float* __restrict__ b1, __bf16* __restrict__ gmI) {
    int idx = blockIdx.x * 256 + threadIdx.x;
    int n = idx >> 4, c8 = (idx & 15) << 3;
    float x0 = x[n * 2], x1 = x[n * 2 + 1];
    float m0 = msg1[n * 2], m1 = msg1[n * 2 + 1];
    bf16x8 hv, lv;
#pragma unroll
    for (int e = 0; e < 8; ++e) {
        int c = c8 + e;
        float v = b1[c];
        v = fmaf(x0, W1r[c * 2], v);
        v = fmaf(x1, W1r[c * 2 + 1], v);
        v = fmaf(m0, W1n[c * 2], v);
        v = fmaf(m1, W1n[c * 2 + 1], v);
        v = v >= 0.f ? v : 0.01f * v;
        __bf16 h = (__bf16)v;
        hv[e] = h;
        lv[e] = (__bf16)(v - (float)h);
    }
    *(bf16x8*)&gmI[(size_t)n * 512 + c8] = hv;
    *(bf16x8*)&gmI[(size_t)n * 512 + 256 + c8] = lv;
}

// ---------------- merged weight prep ----------------
__global__ void prep_all(const float* __restrict__ W2r, const float* __restrict__ W2n,
                         const float* __restrict__ nW1, const float* __restrict__ nW2,
                         const float* __restrict__ eW1, const float* __restrict__ eW2,
                         __bf16* __restrict__ wcat_hi, __bf16* __restrict__ wcat_lo,
                         __bf16* __restrict__ nW1hi, __bf16* __restrict__ nW1lo,
                         __bf16* __restrict__ nW2hi, __bf16* __restrict__ nW2lo,
                         __bf16* __restrict__ eW1hi, __bf16* __restrict__ eW1lo,
                         __bf16* __restrict__ eW2hi, __bf16* __restrict__ eW2lo) {
    int i = blockIdx.x * 256 + threadIdx.x;
    float v; __bf16 *hi, *lo; int off;
    if (i < 65536) {
        int c = i >> 8, k = i & 255;
        v = (k < 128) ? W2r[c * 128 + k] : W2n[c * 128 + (k - 128)];
        hi = wcat_hi; lo = wcat_lo; off = i;
    } else if (i < 131072) {
        off = i - 65536;  v = nW1[off]; hi = nW1hi; lo = nW1lo;
    } else if (i < 262144) {
        off = i - 131072; v = nW2[off]; hi = nW2hi; lo = nW2lo;
    } else if (i < 458752) {
        off = i - 262144; v = eW1[off]; hi = eW1hi; lo = eW1lo;
    } else {
        off = i - 458752; v = eW2[off]; hi = eW2hi; lo = eW2lo;
    }
    __bf16 h = (__bf16)v;
    hi[off] = h;
    lo[off] = (__bf16)(v - (float)h);
}

// ---------------- conv2 GEMM: r9 winner + XCD-bijective block swizzle + setprio ----------------
// BM=64, BN=256, 4 waves, dbuf + counted vmcnt(10). A rows interleaved [hi|lo] stride 512.
// Row-tile = m204-bijective XCD remap of blockIdx.x over nwg tiles (clusters consecutive
// tiles (same batch rows -> same atomic lines) on one XCD's L2).
template <int MODE>
__global__ __launch_bounds__(256, 2)
void conv2_gemm(const __bf16* __restrict__ A,
                const __bf16* __restrict__ whi, const __bf16* __restrict__ wlo,
                const float* __restrict__ bias,
                float* __restrict__ out, int ldo, int M, int nwg,
                const int* __restrict__ aux, const int* __restrict__ aux2) {
    __shared__ __attribute__((aligned(16))) __bf16 A2[2][64 * 64];
    __shared__ __attribute__((aligned(16))) __bf16 B2[2][256 * 64];
    const int tid = threadIdx.x, lane = tid & 63, wv = tid >> 6;
    const int fr = lane & 15, kq = lane >> 4;
    // m204 bijective XCD swizzle: orig -> (xcd, idx) -> contiguous chunk per XCD
    int bid = blockIdx.x;
    {
        int q = nwg >> 3, rm = nwg & 7;
        int xcd = bid & 7, idx = bid >> 3;
        bid = (xcd < rm ? xcd * (q + 1) : rm * (q + 1) + (xcd - rm) * q) + idx;
    }
    const int bm = bid * 64;

    const __bf16* asrc[2]; int adst[2];
#pragma unroll
    for (int j = 0; j < 2; ++j) {
        int a = wv * 2 + j;
        int row = a * 8 + (lane >> 3);
        int slot = (lane & 7) ^ (row & 7);
        int m = bm + row;
        long r;
        if (MODE == 2) r = (m < M) ? (long)(m < GB ? aux[m] : aux2[m - GB]) : 0;
        else           r = (m < M) ? m : (M - 1);
        asrc[j] = A + r * 512 + (slot < 4 ? 0 : 256) + (slot & 3) * 8;
        adst[j] = a * 512;
    }
    const __bf16* bsrc[8]; int bdst[8];
#pragma unroll
    for (int j = 0; j < 8; ++j) {
        int bc = wv * 8 + j;
        int col = bc * 8 + (lane >> 3);
        int slot = (lane & 7) ^ (col & 7);
        bsrc[j] = (slot < 4 ? whi : wlo) + (size_t)col * 256 + (slot & 3) * 8;
        bdst[j] = bc * 512;
    }
    int aoh[4], aol[4], boh[4], bol[4];
#pragma unroll
    for (int mt = 0; mt < 4; ++mt) {
        int row = mt * 16 + fr;
        aoh[mt] = row * 64 + ((kq       ^ (row & 7)) * 8);
        aol[mt] = row * 64 + (((kq | 4) ^ (row & 7)) * 8);
    }
#pragma unroll
    for (int nt = 0; nt < 4; ++nt) {
        int col = wv * 64 + nt * 16 + fr;
        boh[nt] = col * 64 + ((kq       ^ (col & 7)) * 8);
        bol[nt] = col * 64 + (((kq | 4) ^ (col & 7)) * 8);
    }

    f32x4 acc[4][4];
#pragma unroll
    for (int i = 0; i < 4; ++i)
#pragma unroll
        for (int j = 0; j < 4; ++j) acc[i][j] = (f32x4){0.f, 0.f, 0.f, 0.f};

#pragma unroll
    for (int j = 0; j < 2; ++j) g2l16(asrc[j], &A2[0][adst[j]]);
#pragma unroll
    for (int j = 0; j < 8; ++j) g2l16(bsrc[j], &B2[0][bdst[j]]);
#pragma unroll
    for (int j = 0; j < 2; ++j) g2l16(asrc[j] + 32, &A2[1][adst[j]]);
#pragma unroll
    for (int j = 0; j < 8; ++j) g2l16(bsrc[j] + 32, &B2[1][bdst[j]]);

#pragma unroll
    for (int t = 0; t < 8; ++t) {
        const int cur = t & 1;
        if (t < 7) asm volatile("s_waitcnt vmcnt(10)" ::: "memory");
        else       asm volatile("s_waitcnt vmcnt(0)" ::: "memory");
        __builtin_amdgcn_s_barrier();

        bf16x8 ah[4], al[4], bh[4], bl[4];
#pragma unroll
        for (int mt = 0; mt < 4; ++mt) {
            ah[mt] = *(const bf16x8*)&A2[cur][aoh[mt]];
            al[mt] = *(const bf16x8*)&A2[cur][aol[mt]];
        }
#pragma unroll
        for (int nt = 0; nt < 4; ++nt) {
            bh[nt] = *(const bf16x8*)&B2[cur][boh[nt]];
            bl[nt] = *(const bf16x8*)&B2[cur][bol[nt]];
        }
        asm volatile("s_waitcnt lgkmcnt(0)" ::: "memory");
        __builtin_amdgcn_sched_barrier(0);
        __builtin_amdgcn_s_barrier();

        if (t + 2 < 8) {
            int ks = (t + 2) * 32;
#pragma unroll
            for (int j = 0; j < 2; ++j) g2l16(asrc[j] + ks, &A2[cur][adst[j]]);
#pragma unroll
            for (int j = 0; j < 8; ++j) g2l16(bsrc[j] + ks, &B2[cur][bdst[j]]);
        }
        __builtin_amdgcn_s_setprio(1);
#pragma unroll
        for (int mt = 0; mt < 4; ++mt)
#pragma unroll
            for (int nt = 0; nt < 4; ++nt) {
                acc[mt][nt] = __builtin_amdgcn_mfma_f32_16x16x32_bf16(ah[mt], bh[nt], acc[mt][nt], 0, 0, 0);
                acc[mt][nt] = __builtin_amdgcn_mfma_f32_16x16x32_bf16(ah[mt], bl[nt], acc[mt][nt], 0, 0, 0);
                acc[mt][nt] = __builtin_amdgcn_mfma_f32_16x16x32_bf16(al[mt], bh[nt], acc[mt][nt], 0, 0, 0);
            }
        __builtin_amdgcn_s_setprio(0);
    }

    const int q4 = kq * 4;
    const int cb = wv * 64;

    if (MODE == 1) {
        float s0 = 0.f, s1 = 0.f, s2 = 0.f, s3 = 0.f;
        int cur2 = -1;
        float bi0 = bias[cb + 0 * 16 + fr], bi1 = bias[cb + 1 * 16 + fr];
        float bi2 = bias[cb + 2 * 16 + fr], bi3 = bias[cb + 3 * 16 + fr];
#pragma unroll
        for (int mt = 0; mt < 4; ++mt) {
#pragma unroll
            for (int j = 0; j < 4; ++j) {
                int m = bm + mt * 16 + q4 + j;
                if (m < M) {
                    float v0 = acc[mt][0][j] + bi0;
                    float v1 = acc[mt][1][j] + bi1;
                    float v2 = acc[mt][2][j] + bi2;
                    float v3 = acc[mt][3][j] + bi3;
                    v0 = v0 >= 0.f ? v0 : 0.01f * v0;
                    v1 = v1 >= 0.f ? v1 : 0.01f * v1;
                    v2 = v2 >= 0.f ? v2 : 0.01f * v2;
                    v3 = v3 >= 0.f ? v3 : 0.01f * v3;
                    int b = aux[m];
                    if (b != cur2) {
                        if (cur2 >= 0) {
                            atomicAdd(&out[(size_t)cur2 * ldo + cb + 0 * 16 + fr], s0);
                            atomicAdd(&out[(size_t)cur2 * ldo + cb + 1 * 16 + fr], s1);
                            atomicAdd(&out[(size_t)cur2 * ldo + cb + 2 * 16 + fr], s2);
                            atomicAdd(&out[(size_t)cur2 * ldo + cb + 3 * 16 + fr], s3);
                        }
                        cur2 = b; s0 = v0; s1 = v1; s2 = v2; s3 = v3;
                    } else {
                        s0 += v0; s1 += v1; s2 += v2; s3 += v3;
                    }
                }
            }
        }
        if (cur2 >= 0) {
            atomicAdd(&out[(size_t)cur2 * ldo + cb + 0 * 16 + fr], s0);
            atomicAdd(&out[(size_t)cur2 * ldo + cb + 1 * 16 + fr], s1);
            atomicAdd(&out[(size_t)cur2 * ldo + cb + 2 * 16 + fr], s2);
            atomicAdd(&out[(size_t)cur2 * ldo + cb + 3 * 16 + fr], s3);
        }
    } else {
#pragma unroll
        for (int mt = 0; mt < 4; ++mt) {
#pragma unroll
            for (int j = 0; j < 4; ++j) {
                int m = bm + mt * 16 + q4 + j;
                if (m >= M) continue;
                int orow = (m < GB) ? m : m - GB;
                int ocol = (m < GB) ? 256 : 512;
                size_t obase = (size_t)orow * ldo + ocol;
#pragma unroll
                for (int nt = 0; nt < 4; ++nt) {
                    int cc = cb + nt * 16 + fr;
                    float v = acc[mt][nt][j] + bias[cc];
                    v = v >= 0.f ? v : 0.01f * v;
                    out[obase + cc] = v;
                }
            }
        }
    }
}

// ---------------- MLP GEMM: BM=64 x BN=64 per block, wave = 16 rows x 64 cols ----------------
template <int PRESPLIT, int OSPLIT>
__global__ __launch_bounds__(256, 4)
void mlp_gemm(const float* __restrict__ Af,
              const __bf16* __restrict__ Agh, const __bf16* __restrict__ Agl, int lda,
              const __bf16* __restrict__ whi, const __bf16* __restrict__ wlo,
              const float* __restrict__ bias,
              float* __restrict__ out, __bf16* __restrict__ outh, __bf16* __restrict__ outl,
              int ldo, int M, int K, int ctiles) {
    __shared__ __bf16 Ah[64][40], Al[64][40];
    const int bm = (blockIdx.x / ctiles) * 64;
    const int bn = (blockIdx.x % ctiles) * 64;
    const int tid = threadIdx.x, lane = tid & 63, wv = tid >> 6;

    const int sar = tid >> 2;
    const int sak = (tid & 3) * 8;
    const int arow = bm + sar;
    long asrc = arow < M ? arow : M - 1;
    const float*  Arf = PRESPLIT ? nullptr : (Af + (size_t)asrc * lda);
    const __bf16* Arh = PRESPLIT ? (Agh + (size_t)asrc * lda) : nullptr;
    const __bf16* Arl = PRESPLIT ? (Agl + (size_t)asrc * lda) : nullptr;

    const int fr = lane & 15, kg = (lane >> 4) * 8;

    const __bf16* bph[4];
    const __bf16* bpl[4];
#pragma unroll
    for (int nt = 0; nt < 4; ++nt) {
        bph[nt] = whi + (size_t)(bn + nt * 16 + fr) * K + kg;
        bpl[nt] = wlo + (size_t)(bn + nt * 16 + fr) * K + kg;
    }

    f32x4 acc[4];
#pragma unroll
    for (int j = 0; j < 4; ++j) acc[j] = (f32x4){0.f, 0.f, 0.f, 0.f};

    for (int ks = 0; ks < K; ks += 32) {
        uint4 hv, lv;
        if (PRESPLIT) {
            hv = *(const uint4*)(Arh + ks + sak);
            lv = *(const uint4*)(Arl + ks + sak);
        } else {
            float4 a0 = *(const float4*)(Arf + ks + sak);
            float4 a1 = *(const float4*)(Arf + ks + sak + 4);
            float va[8] = {a0.x, a0.y, a0.z, a0.w, a1.x, a1.y, a1.z, a1.w};
            bf16x8 h8, l8;
#pragma unroll
            for (int e = 0; e < 8; ++e) {
                float v = va[e];
                __bf16 h = (__bf16)v;
                h8[e] = h;
                l8[e] = (__bf16)(v - (float)h);
            }
            hv = *(uint4*)&h8;
            lv = *(uint4*)&l8;
        }
        __syncthreads();
        *(uint4*)&Ah[sar][sak] = hv;
        *(uint4*)&Al[sar][sak] = lv;
        __syncthreads();

        bf16x8 ahf, alf, bh[4], bl[4];
        ahf = *(const bf16x8*)&Ah[wv * 16 + fr][kg];
        alf = *(const bf16x8*)&Al[wv * 16 + fr][kg];
#pragma unroll
        for (int nt = 0; nt < 4; ++nt) {
            bh[nt] = *(const bf16x8*)(bph[nt] + ks);
            bl[nt] = *(const bf16x8*)(bpl[nt] + ks);
        }
#pragma unroll
        for (int nt = 0; nt < 4; ++nt) {
            acc[nt] = __builtin_amdgcn_mfma_f32_16x16x32_bf16(ahf, bh[nt], acc[nt], 0, 0, 0);
            acc[nt] = __builtin_amdgcn_mfma_f32_16x16x32_bf16(ahf, bl[nt], acc[nt], 0, 0, 0);
            acc[nt] = __builtin_amdgcn_mfma_f32_16x16x32_bf16(alf, bh[nt], acc[nt], 0, 0, 0);
        }
    }

    const int q4 = (lane >> 4) * 4;
#pragma unroll
    for (int j = 0; j < 4; ++j) {
        int m = bm + wv * 16 + q4 + j;
        if (m >= M) continue;
        size_t obase = (size_t)m * ldo;
#pragma unroll
        for (int nt = 0; nt < 4; ++nt) {
            int cc = bn + nt * 16 + fr;
            float v = tanhf(acc[nt][j] + bias[cc]);
            if (OSPLIT) {
                __bf16 h = (__bf16)v;
                outh[obase + cc] = h;
                outl[obase + cc] = (__bf16)(v - (float)h);
            } else {
                out[obase + cc] = v;
            }
        }
    }
}

// ---------------- output head: wave per (b,o), coalesced + shfl reduce ----------------
__global__ void outhead_kernel(const float* __restrict__ h, const float* __restrict__ W,
                               const float* __restrict__ bias, float* __restrict__ yp,
                               int total, int nout) {
    int w = (blockIdx.x * 256 + threadIdx.x) >> 6;
    int lane = threadIdx.x & 63;
    if (w >= total) return;
    int b = w / nout, o = w - b * nout;
    const float4* hr = (const float4*)(h + (size_t)b * 512) + lane * 2;
    const float4* wr = (const float4*)(W + (size_t)o * 512) + lane * 2;
    float4 h0 = hr[0], h1 = hr[1], w0 = wr[0], w1 = wr[1];
    float s = h0.x * w0.x + h0.y * w0.y + h0.z * w0.z + h0.w * w0.w +
              h1.x * w1.x + h1.y * w1.y + h1.z * w1.z + h1.w * w1.w;
#pragma unroll
    for (int off = 32; off >= 1; off >>= 1) s += __shfl_down(s, off);
    if (lane == 0) yp[w] = s + bias[o];
}

// ---------------- losses ----------------
__global__ void loss_kernel(const float* __restrict__ ypx, const float* __restrict__ ypA,
                            const float* __restrict__ y_x, const float* __restrict__ y_A,
                            float* __restrict__ out) {
    int b = blockIdx.x * 256 + threadIdx.x;
    if (b >= GB) return;
#pragma unroll
    for (int j = 0; j < 2; ++j) {
        float p  = ypx[b * 4 + j];
        float a  = p * p + 1e-7f;
        float mu = ypx[b * 4 + 2 + j];
        float e  = (y_x[b * 2 + j] - mu) / a;
        out[b * 2 + j] = e * e + logf(a);
    }
    float p  = ypA[b * 2 + 0];
    float a  = p * p + 1e-7f;
    float mu = ypA[b * 2 + 1];
    float e  = (y_A[b] - mu) / a;
    out[2 * GB + b] = e * e + logf(a);
}

extern "C" void kernel_launch(void* const* d_in, const int* in_sizes, int n_in,
                              void* d_out, int out_size, void* d_ws, size_t ws_size,
                              hipStream_t stream) {
    const float* x_x     = (const float*)d_in[0];
    const float* y_x     = (const float*)d_in[1];
    const int*   ei_x    = (const int*)d_in[2];
    const int*   batch_x = (const int*)d_in[3];
    const float* x_A     = (const float*)d_in[4];
    const float* y_A     = (const float*)d_in[5];
    const int*   ei_A    = (const int*)d_in[6];
    const int*   batch_A = (const int*)d_in[7];
    const int*   idi_A   = (const int*)d_in[8];
    const int*   idj_A   = (const int*)d_in[9];
    const float* W1r = (const float*)d_in[10];
    const float* W1n = (const float*)d_in[11];
    const float* b1  = (const float*)d_in[12];
    const float* W2r = (const float*)d_in[13];
    const float* W2n = (const float*)d_in[14];
    const float* b2  = (const float*)d_in[15];
    const float* nW1 = (const float*)d_in[16];
    const float* nb1 = (const float*)d_in[17];
    const float* nW2 = (const float*)d_in[18];
    const float* nb2 = (const float*)d_in[19];
    const float* nW3 = (const float*)d_in[20];
    const float* nb3 = (const float*)d_in[21];
    const float* eW1 = (const float*)d_in[22];
    const float* eb1 = (const float*)d_in[23];
    const float* eW2 = (const float*)d_in[24];
    const float* eb2 = (const float*)d_in[25];
    const float* eW3 = (const float*)d_in[26];
    const float* eb3 = (const float*)d_in[27];

    // ---- workspace layout ----
    __bf16* gmI  = (__bf16*)d_ws;                    // GN*512 (interleaved hi|lo)
    float*  msg1 = (float*)(gmI + (size_t)GN * 512); // 2*GN*2
    float*  rgx  = msg1 + (size_t)2 * GN * 2;        // GB*256
    float*  use  = rgx  + (size_t)GB * 256;          // GB*768
    __bf16* wcat_hi = (__bf16*)(use + (size_t)GB * 768);
    __bf16* wcat_lo = wcat_hi + 65536;
    __bf16* nW1hi = wcat_lo + 65536;
    __bf16* nW1lo = nW1hi + 65536;
    __bf16* nW2hi = nW1lo + 65536;
    __bf16* nW2lo = nW2hi + 131072;
    __bf16* eW1hi = nW2lo + 131072;
    __bf16* eW1lo = eW1hi + 196608;
    __bf16* eW2hi = eW1lo + 196608;
    __bf16* eW2lo = eW2hi + 131072;
    int* rowptr = (int*)(eW2lo + 131072);            // 2*GN
    int* cursor = rowptr + 2 * GN;                   // 2*GN
    int* eidx   = cursor + 2 * GN;                   // 2*GE
    int* csum   = eidx + 2 * GE;                     // 256
    char* wend  = (char*)(csum + 256);
    // aliases into gmI region (dead after sel-GEMM):
    __bf16* h1h = gmI;
    __bf16* h1l = h1h + (size_t)GB * 256;
    float*  h2  = (float*)(h1l + (size_t)GB * 256);
    float*  ypx = h2 + (size_t)GB * 512;
    float*  ypA = ypx + (size_t)GB * 4;

    size_t need = (size_t)(wend - (char*)d_ws);
    if (ws_size < need) return;

    float* out = (float*)d_out;

    // merged weight prep
    prep_all<<<2304, 256, 0, stream>>>(W2r, W2n, nW1, nW2, eW1, eW2,
                                       wcat_hi, wcat_lo, nW1hi, nW1lo, nW2hi, nW2lo,
                                       eW1hi, eW1lo, eW2hi, eW2lo);

    // CSR + msg1 for BOTH graphs, fused
    hipMemsetAsync(rowptr, 0, (size_t)2 * GN * sizeof(int), stream);
    deg2_kernel<<<(2 * GE + 255) / 256, 256, 0, stream>>>(ei_x + GE, ei_A + GE, rowptr);
    scan1_kernel<<<2 * NCHUNK, 512, 0, stream>>>(rowptr, csum);
    scan2_kernel<<<2, 128, 0, stream>>>(csum);
    scan3_kernel<<<(2 * GN + 255) / 256, 256, 0, stream>>>(rowptr, cursor, csum);
    fill2_kernel<<<(2 * GE + 255) / 256, 256, 0, stream>>>(ei_x, ei_x + GE, ei_A, ei_A + GE,
                                                           cursor, eidx);
    msg1_kernel<<<(2 * GN + 255) / 256, 256, 0, stream>>>(x_x, x_A, rowptr, cursor, eidx, msg1);

    // zero both readout buffers in one shot (contiguous)
    hipMemsetAsync(rgx, 0, (size_t)(GB * 256 + GB * 768) * sizeof(float), stream);

    const int conv2_grid = GN / 64;                 // 3125
    const int sel_grid   = (2 * GB + 63) / 64;      // 313

    for (int g = 0; g < 2; ++g) {
        const float* x = g == 0 ? x_x : x_A;
        const int* rp  = rowptr + g * GN;
        const int* cu  = cursor + g * GN;
        const int* ei  = eidx + (size_t)g * GE;
        const int* bat = g == 0 ? batch_x : batch_A;

        conv1_kernel<<<GN * 16 / 256, 256, 0, stream>>>(x, msg1 + (size_t)g * GN * 2,
                                                        W1r, W1n, b1, gmI);
        msg2_csr_kernel<<<GN / 4, 256, 0, stream>>>(gmI, rp, cu, ei, gmI);

        if (g == 0) {
            conv2_gemm<1><<<conv2_grid, 256, 0, stream>>>(
                gmI, wcat_hi, wcat_lo, b2, rgx, 256, GN, conv2_grid, bat, nullptr);
        } else {
            conv2_gemm<1><<<conv2_grid, 256, 0, stream>>>(
                gmI, wcat_hi, wcat_lo, b2, use, 768, GN, conv2_grid, bat, nullptr);
            conv2_gemm<2><<<sel_grid, 256, 0, stream>>>(
                gmI, wcat_hi, wcat_lo, b2, use, 768, 2 * GB, sel_grid, idi_A, idj_A);
        }
    }

    const int mlp_mt = (GB + 63) / 64;   // 157

    // node MLP (h1/h2 alias gmI region; gm dead now)
    mlp_gemm<0, 1><<<mlp_mt * 4, 256, 0, stream>>>(
        rgx, nullptr, nullptr, 256, nW1hi, nW1lo, nb1,
        nullptr, h1h, h1l, 256, GB, 256, 4);
    mlp_gemm<1, 0><<<mlp_mt * 8, 256, 0, stream>>>(
        nullptr, h1h, h1l, 256, nW2hi, nW2lo, nb2,
        h2, nullptr, nullptr, 512, GB, 256, 8);
    outhead_kernel<<<(GB * 4 * 64 + 255) / 256, 256, 0, stream>>>(h2, nW3, nb3, ypx, GB * 4, 4);

    // edge MLP
    mlp_gemm<0, 1><<<mlp_mt * 4, 256, 0, stream>>>(
        use, nullptr, nullptr, 768, eW1hi, eW1lo, eb1,
        nullptr, h1h, h1l, 256, GB, 768, 4);
    mlp_gemm<1, 0><<<mlp_mt * 8, 256, 0, stream>>>(
        nullptr, h1h, h1l, 256, eW2hi, eW2lo, eb2,
        h2, nullptr, nullptr, 512, GB, 256, 8);
    outhead_kernel<<<(GB * 2 * 64 + 255) / 256, 256, 0, stream>>>(h2, eW3, eb3, ypA, GB * 2, 2);

    loss_kernel<<<(GB + 255) / 256, 256, 0, stream>>>(ypx, ypA, y_x, y_A, out);
}